// Round 8
// baseline (304.983 us; speedup 1.0000x reference)
//
#include <hip/hip_runtime.h>
#include <stdint.h>

typedef __attribute__((ext_vector_type(8))) short bf16x8_t;   // 8 bf16 in 4 VGPRs
typedef __attribute__((ext_vector_type(4))) float f32x4_t;

#define DI __device__ __forceinline__
#define SBAR() asm volatile("s_barrier" ::: "memory")
#define VMW(n) asm volatile("s_waitcnt vmcnt(" #n ")" ::: "memory")

DI unsigned short f2b(float f) {
  union { float f; unsigned int u; } c; c.f = f;
  unsigned int u = c.u + 0x7FFFu + ((c.u >> 16) & 1u);   // RNE
  return (unsigned short)(u >> 16);
}
DI unsigned int pack2(float lo, float hi) {
  return (unsigned int)f2b(lo) | ((unsigned int)f2b(hi) << 16);
}
DI float b2f(unsigned short h) {
  union { unsigned int u; float f; } c; c.u = ((unsigned int)h) << 16;
  return c.f;
}
DI float silu_f(float z) { return z / (1.0f + __expf(-z)); }

// async global->LDS, 16B per lane; LDS dst = wave-uniform base + lane*16B
DI void load_lds16(const unsigned short* g, unsigned short* l) {
  __builtin_amdgcn_global_load_lds(
      (const __attribute__((address_space(1))) unsigned int*)g,
      (__attribute__((address_space(3))) unsigned int*)l,
      16, 0, 0);
}

// ---------------------------------------------------------------- prep mega-kernel
struct PrepP {
  const float *Wh, *Wo, *Wqk, *x, *g, *b;
  unsigned short *WT, *WoT, *normed;
};

__global__ __launch_bounds__(256) void prep_kernel(PrepP p) {
  const int blk = blockIdx.x;
  const int tx = threadIdx.x & 31, ty = threadIdx.x >> 5;
  if (blk < 6272) {
    const float* in; unsigned short* out; int R, C, gx;
    if (blk < 4096)      { in = p.Wh;  out = p.WT;                 R = 1024; C = 4096; gx = blk; }
    else if (blk < 6144) { in = p.Wo;  out = p.WoT;                R = 2048; C = 1024; gx = blk - 4096; }
    else                 { in = p.Wqk; out = p.WT + 4096 * 1024;   R = 1024; C = 128;  gx = blk - 6144; }
    const int xTiles = C >> 5;
    const int c0 = (gx % xTiles) * 32, r0 = (gx / xTiles) * 32;
    __shared__ float tile[32][33];
#pragma unroll
    for (int i = 0; i < 4; ++i)
      tile[ty + 8 * i][tx] = in[(long)(r0 + ty + 8 * i) * C + c0 + tx];
    __syncthreads();
#pragma unroll
    for (int i = 0; i < 4; ++i)
      out[(long)(c0 + ty + 8 * i) * R + r0 + tx] = f2b(tile[tx][ty + 8 * i]);
  } else {
    const int row = blk - 6272, tid = threadIdx.x;
    __shared__ float red[8];
    float4 v = ((const float4*)(p.x + (long)row * 1024))[tid];
    float s = v.x + v.y + v.z + v.w;
    float ss = v.x * v.x + v.y * v.y + v.z * v.z + v.w * v.w;
    for (int o = 32; o > 0; o >>= 1) { s += __shfl_down(s, o); ss += __shfl_down(ss, o); }
    const int wave = tid >> 6, lane = tid & 63;
    if (lane == 0) { red[wave * 2] = s; red[wave * 2 + 1] = ss; }
    __syncthreads();
    if (tid == 0) {
      float S = red[0] + red[2] + red[4] + red[6];
      float SS = red[1] + red[3] + red[5] + red[7];
      float mu = S * (1.0f / 1024.0f);
      float var = SS * (1.0f / 1024.0f) - mu * mu;
      red[0] = mu; red[1] = rsqrtf(var + 1e-5f);
    }
    __syncthreads();
    const float mu = red[0], rstd = red[1];
    float4 gg = ((const float4*)p.g)[tid];
    float4 bb = ((const float4*)p.b)[tid];
    ushort4 o;
    o.x = f2b((v.x - mu) * rstd * gg.x + bb.x);
    o.y = f2b((v.y - mu) * rstd * gg.y + bb.y);
    o.z = f2b((v.z - mu) * rstd * gg.z + bb.z);
    o.w = f2b((v.w - mu) * rstd * gg.w + bb.w);
    ((ushort4*)(p.normed + (long)row * 1024))[tid] = o;
  }
}

// ---------------------------------------------------------------- reduce 8 bf16 slabs -> bf16
__global__ __launch_bounds__(256) void reduce_cvt(
    const unsigned short* __restrict__ part, unsigned short* __restrict__ out) {
  const int idx = blockIdx.x * 256 + threadIdx.x;
  const int b = idx >> 16, i = idx & 65535;
  float4 s = make_float4(0.f, 0.f, 0.f, 0.f);
#pragma unroll
  for (int sl = 0; sl < 8; ++sl) {
    ushort4 v = ((const ushort4*)part)[(long)(b * 8 + sl) * 65536 + i];
    s.x += b2f(v.x); s.y += b2f(v.y); s.z += b2f(v.z); s.w += b2f(v.w);
  }
  ushort4 o;
  o.x = f2b(s.x); o.y = f2b(s.y); o.z = f2b(s.z); o.w = f2b(s.w);
  ((ushort4*)out)[(long)b * 65536 + i] = o;
}

// ---------------------------------------------------------------- 8-wave 256x128 deep-pipelined GEMM1
// R10 (proven): 3-slot/2-blocks-per-CU geometry, counted VMW(3)/0, 1 SBAR/tile.
struct G8P {
  const unsigned short* A;
  const unsigned short* B;
  const float* bias;          // b_hidden[4096]
  const float* bias2;         // b_qk[128]
  const float* gamma;         // os_gamma [4][128]
  const float* beta;          // os_beta  [4][128]
  unsigned short* vTout;      // [4][2048 e][2048 n]
  unsigned short* gateOut;    // [8192][2048]
  unsigned short* qqO;        // [8192][128]
  unsigned short* lqO;
  unsigned short* qkhO;
  unsigned short* lkTO;       // [4][128][2048]
};

__global__ __launch_bounds__(512, 4) void gemm8p(G8P p) {
  extern __shared__ unsigned char lds[];   // 3 * 24576 = 73728 B dynamic
  const int tid  = threadIdx.x;
  const int lane = tid & 63;
  const int wave = tid >> 6;
  const bool qk = blockIdx.x < 32;
  int bx, by;
  if (qk) { bx = blockIdx.x; by = 32; }                 // B rows 4096..4223
  else    { const int vg = blockIdx.x - 32; bx = vg >> 5; by = vg & 31; }
  const int wm = (wave & 1) * 128;
  const int wn = (wave >> 1) * 32;
  const int lm = lane & 15;
  const int kb = lane >> 4;

  // ---- staging coords (pre-swizzled global source; LDS lands linear) ----
  const int rA  = tid >> 2;                                    // 0..127
  const int kby = ((tid & 3) << 4) ^ (((rA >> 1) & 3) << 4);   // 2-way swizzle
  const unsigned short* gA0 = p.A + (long)(bx * 256 + rA) * 1024 + (kby >> 1);
  const unsigned short* gA1 = gA0 + 128 * 1024;
  const int brow = qk ? 4096 : by * 128;
  const unsigned short* gB0 = p.B + (long)(brow + rA) * 1024 + (kby >> 1);

  // ---- fragment-read lane constant ((row>>1)&3 == (lm>>1)&3 for all reps) ----
  const int fxor = (kb << 4) ^ (((lm >> 1) & 3) << 4);

  f32x4_t acc[8][2];
#pragma unroll
  for (int i = 0; i < 8; ++i)
#pragma unroll
    for (int j = 0; j < 2; ++j) acc[i][j] = (f32x4_t){0.f, 0.f, 0.f, 0.f};

  auto stageA = [&](int t) {
    unsigned short* l = (unsigned short*)(lds + (t % 3) * 24576 + wave * 1024);
    load_lds16(gA0 + t * 32, l);
    load_lds16(gA1 + t * 32, (unsigned short*)((unsigned char*)l + 8192));
  };
  auto stageB = [&](int t) {   // 128 rows x 64B = 8KB = 1 load/thread
    unsigned short* l = (unsigned short*)(lds + (t % 3) * 24576 + 16384 + wave * 1024);
    load_lds16(gB0 + t * 32, l);
  };

  // prologue: 2 tiles in flight (6 loads/thread)
#pragma unroll
  for (int u = 0; u < 2; ++u) { stageA(u); stageB(u); }
  VMW(3);
  SBAR();

  constexpr int NT = 16;   // K=1024 / BK=32
#pragma unroll 1
  for (int t = 0; t < NT; ++t) {
    const unsigned char* slot = lds + (t % 3) * 24576;
    bf16x8_t bF[2], aF[4];
#pragma unroll
    for (int j = 0; j < 2; ++j)
      bF[j] = *(const bf16x8_t*)(slot + 16384 + (wn + j * 16 + lm) * 64 + fxor);
#pragma unroll
    for (int i = 0; i < 4; ++i)
      aF[i] = *(const bf16x8_t*)(slot + (wm + i * 16 + lm) * 64 + fxor);
    if (t <= NT - 3) stageA(t + 2);
    __builtin_amdgcn_s_setprio(1);
#pragma unroll
    for (int i = 0; i < 4; ++i)
#pragma unroll
      for (int j = 0; j < 2; ++j)
        acc[i][j] = __builtin_amdgcn_mfma_f32_16x16x32_bf16(aF[i], bF[j], acc[i][j], 0, 0, 0);
    __builtin_amdgcn_s_setprio(0);
#pragma unroll
    for (int i = 0; i < 4; ++i)
      aF[i] = *(const bf16x8_t*)(slot + (wm + 64 + i * 16 + lm) * 64 + fxor);
    if (t <= NT - 3) stageB(t + 2);
    __builtin_amdgcn_s_setprio(1);
#pragma unroll
    for (int i = 0; i < 4; ++i)
#pragma unroll
      for (int j = 0; j < 2; ++j)
        acc[i + 4][j] = __builtin_amdgcn_mfma_f32_16x16x32_bf16(aF[i], bF[j], acc[i + 4][j], 0, 0, 0);
    __builtin_amdgcn_s_setprio(0);
    if (t <= NT - 3)      { VMW(3); }
    else if (t == NT - 2) { VMW(0); }
    SBAR();   // single barrier per tile
  }

  // ---------------- epilogue ----------------
  if (qk) {
    // silu -> LDS [256][136] -> OffsetScale+RoPE. All 8 waves write (BN=128).
    unsigned short* q16 = (unsigned short*)lds;   // 69632 B <= 73728
#pragma unroll
    for (int i = 0; i < 8; ++i) {
      const int rloc = wm + i * 16 + (lane >> 4) * 4;   // 0..255
#pragma unroll
      for (int j = 0; j < 2; ++j) {
        const int cl = wn + j * 16 + lm;                // 0..127
        const float bb = p.bias2[cl];
#pragma unroll
        for (int r = 0; r < 4; ++r)
          q16[(rloc + r) * 136 + cl] = f2b(silu_f(acc[i][j][r] + bb));
      }
    }
    __syncthreads();
    const int j = tid & 63;
    const int rq = tid >> 6;                              // 0..7
    const float freq = powf(10000.0f, (float)j * (1.0f / 64.0f));
    float ga[4], gb[4], ea[4], eb[4];
#pragma unroll
    for (int h = 0; h < 4; ++h) {
      ga[h] = p.gamma[h * 128 + j];  gb[h] = p.gamma[h * 128 + 64 + j];
      ea[h] = p.beta[h * 128 + j];   eb[h] = p.beta[h * 128 + 64 + j];
    }
    unsigned short* outs[3] = {p.qqO, p.lqO, p.qkhO};
    for (int rr = 0; rr < 32; ++rr) {
      const int row = rr * 8 + rq;                        // 0..255
      const float x1 = b2f(q16[row * 136 + j]);
      const float x2 = b2f(q16[row * 136 + 64 + j]);
      const int tok = bx * 256 + row;
      const int pos = tok & 2047, bidx = tok >> 11;
      const float ang = (float)pos * freq;
      const float sn = sinf(ang), cs = cosf(ang);
#pragma unroll
      for (int h = 0; h < 3; ++h) {
        const float y1 = x1 * ga[h] + ea[h], y2 = x2 * gb[h] + eb[h];
        outs[h][(long)tok * 128 + j] = f2b(y1 * cs - y2 * sn);
        outs[h][(long)tok * 128 + 64 + j] = f2b(y2 * cs + y1 * sn);
      }
      const float y1 = x1 * ga[3] + ea[3], y2 = x2 * gb[3] + eb[3];
      p.lkTO[((long)bidx * 128 + j) * 2048 + pos] = f2b(y1 * cs - y2 * sn);
      p.lkTO[((long)bidx * 128 + 64 + j) * 2048 + pos] = f2b(y2 * cs + y1 * sn);
    }
  } else if (by < 16) {
    // v half: silu+bias, pack pairs, 256x128 transpose via [128][128]-uint LDS
    // (64KB), chunk-XOR (e&7) kills conflicts; coalesced 512B vT row stores.
    unsigned int* Cx = (unsigned int*)lds;
#pragma unroll
    for (int i = 0; i < 8; ++i) {
      const int c0 = (wm + i * 16) / 2 + (lane >> 4) * 2;   // even uint col 0..127
#pragma unroll
      for (int j = 0; j < 2; ++j) {
        const int e = wn + j * 16 + lm;                     // 0..127
        const float bb = p.bias[by * 128 + e];
        const float s0 = silu_f(acc[i][j][0] + bb);
        const float s1 = silu_f(acc[i][j][1] + bb);
        const float s2 = silu_f(acc[i][j][2] + bb);
        const float s3 = silu_f(acc[i][j][3] + bb);
        const int x = (e & 7) << 2;
        Cx[e * 128 + (c0 ^ x)]     = pack2(s0, s1);
        Cx[e * 128 + (c0 ^ x) + 1] = pack2(s2, s3);
      }
    }
    __syncthreads();
    const int bq = bx >> 3, nloc0 = (bx & 7) * 256, e0g = by * 128;
    unsigned short* dstBase = p.vTout + ((long)(bq * 2048 + e0g)) * 2048 + nloc0;
#pragma unroll
    for (int rep = 0; rep < 8; ++rep) {
      const int flat = rep * 512 + tid;
      const int e = flat >> 5, q = flat & 31;
      uint4 val = *(const uint4*)(Cx + e * 128 + ((q ^ (e & 7)) << 2));
      *(uint4*)(dstBase + (long)e * 2048 + q * 8) = val;
    }
  } else {
    // gate half: cols 2048 + (by-16)*128 ..
#pragma unroll
    for (int i = 0; i < 8; ++i) {
      const int row0 = bx * 256 + wm + i * 16 + (lane >> 4) * 4;
#pragma unroll
      for (int j = 0; j < 2; ++j) {
        const int colg = (by - 16) * 128 + wn + j * 16 + lm;   // 0..2047
        const float bb = p.bias[2048 + colg];
#pragma unroll
        for (int r = 0; r < 4; ++r)
          p.gateOut[(long)(row0 + r) * 2048 + colg] =
              f2b(silu_f(acc[i][j][r] + bb));
      }
    }
  }
}

// ---------------------------------------------------------------- QUADLIN: A3 = gate*(attn@vg + lq@lkv)
struct GQLP {
  const unsigned short* attn;   // [32][256][256]
  const unsigned short* vT;     // [4][2048][2048]
  const unsigned short* lq;     // [8192][128]
  const unsigned short* lkvT;   // [4][2048][128]
  const unsigned short* gateIn; // [8192][2048]
  unsigned short* outU;         // A3 [8192][2048]
};

__global__ __launch_bounds__(512, 4) void gemmQL(GQLP p) {
  extern __shared__ unsigned char lds[];   // 3 * 24576 = 73728 B dynamic
  const int tid  = threadIdx.x;
  const int lane = tid & 63;
  const int wave = tid >> 6;
  const int z  = blockIdx.x >> 4;    // 0..31 (b*8+g)
  const int by = blockIdx.x & 15;    // 0..15 (n-tile of 2048, 128 wide)
  const int b = z >> 3, g = z & 7;
  const int wm = (wave & 1) * 128;
  const int wn = (wave >> 1) * 32;
  const int lm = lane & 15;
  const int kb = lane >> 4;

  const int rA  = tid >> 2;                                    // 0..127
  const int kby = ((tid & 3) << 4) ^ (((rA >> 1) & 3) << 4);
  const int swz = kby >> 1;                                    // shorts
  const unsigned short* a1 = p.attn + (long)z * 65536 + rA * 256 + swz;
  const unsigned short* a2 = p.lq + ((long)z * 256 + rA) * 128 + swz;
  const unsigned short* b1 = p.vT + (long)b * 4194304 + (long)(by * 128 + rA) * 2048 + g * 256 + swz;
  const unsigned short* b2 = p.lkvT + (long)b * 262144 + (by * 128 + rA) * 128 + swz;
  const int fxor = (kb << 4) ^ (((lm >> 1) & 3) << 4);

  f32x4_t acc[8][2];
#pragma unroll
  for (int i = 0; i < 8; ++i)
#pragma unroll
    for (int j = 0; j < 2; ++j) acc[i][j] = (f32x4_t){0.f, 0.f, 0.f, 0.f};

  auto stageA = [&](int tt) {
    unsigned char* base = lds + (tt % 3) * 24576;
    unsigned short* l  = (unsigned short*)(base + wave * 1024);
    unsigned short* lh = (unsigned short*)(base + wave * 1024 + 8192);
    if (tt < 8) { load_lds16(a1 + tt * 32, l); load_lds16(a1 + 128 * 256 + tt * 32, lh); }
    else { const int k2 = (tt - 8) * 32;
           load_lds16(a2 + k2, l); load_lds16(a2 + 128 * 128 + k2, lh); }
  };
  auto stageB = [&](int tt) {   // 128 rows x 64B = 8KB = 1 load/thread
    unsigned short* l = (unsigned short*)(lds + (tt % 3) * 24576 + 16384 + wave * 1024);
    if (tt < 8) load_lds16(b1 + tt * 32, l);
    else        load_lds16(b2 + (tt - 8) * 32, l);
  };

#pragma unroll
  for (int u = 0; u < 2; ++u) { stageA(u); stageB(u); }   // 6 in flight
  VMW(3);
  SBAR();

  constexpr int NT = 12;   // 8 (K=256 phase1) + 4 (K=128 phase2)
#pragma unroll 1
  for (int t = 0; t < NT; ++t) {
    const unsigned char* slot = lds + (t % 3) * 24576;
    bf16x8_t bF[2], aF[4];
#pragma unroll
    for (int j = 0; j < 2; ++j)
      bF[j] = *(const bf16x8_t*)(slot + 16384 + (wn + j * 16 + lm) * 64 + fxor);
#pragma unroll
    for (int i = 0; i < 4; ++i)
      aF[i] = *(const bf16x8_t*)(slot + (wm + i * 16 + lm) * 64 + fxor);
    if (t <= NT - 3) stageA(t + 2);
    __builtin_amdgcn_s_setprio(1);
#pragma unroll
    for (int i = 0; i < 4; ++i)
#pragma unroll
      for (int j = 0; j < 2; ++j)
        acc[i][j] = __builtin_amdgcn_mfma_f32_16x16x32_bf16(aF[i], bF[j], acc[i][j], 0, 0, 0);
    __builtin_amdgcn_s_setprio(0);
#pragma unroll
    for (int i = 0; i < 4; ++i)
      aF[i] = *(const bf16x8_t*)(slot + (wm + 64 + i * 16 + lm) * 64 + fxor);
    if (t <= NT - 3) stageB(t + 2);
    __builtin_amdgcn_s_setprio(1);
#pragma unroll
    for (int i = 0; i < 4; ++i)
#pragma unroll
      for (int j = 0; j < 2; ++j)
        acc[i + 4][j] = __builtin_amdgcn_mfma_f32_16x16x32_bf16(aF[i], bF[j], acc[i + 4][j], 0, 0, 0);
    __builtin_amdgcn_s_setprio(0);
    if (t <= NT - 3)      { VMW(3); }
    else if (t == NT - 2) { VMW(0); }
    SBAR();
  }

  // epilogue: A3 = gate * acc
#pragma unroll
  for (int i = 0; i < 8; ++i) {
    const int row0 = z * 256 + wm + i * 16 + (lane >> 4) * 4;
#pragma unroll
    for (int j = 0; j < 2; ++j) {
      const int col = by * 128 + wn + j * 16 + lm;
#pragma unroll
      for (int r = 0; r < 4; ++r) {
        const long idx = (long)(row0 + r) * 2048 + col;
        p.outU[idx] = f2b(b2f(p.gateIn[idx]) * acc[i][j][r]);
      }
    }
  }
}

// ---------------------------------------------------------------- 128^2 pipelined GEMM (Wo / LKV)
// R11: gemmWo was 98KB LDS -> 1 block/CU, 256 blocks = 1 pass with ZERO
// cross-block overlap (the config R10 proved costs ~18%). New shared skeleton:
// BM=BN=128, 8 waves (2m x 4n, 64x32 each), acc[4][2], 16KB/slot x 3-slot =
// 48KB -> 2 blocks/CU resident at grid 512. 2 loads/thread/tile (A=1, B=1),
// counted VMW(2)/0, 1 SBAR/tile, 2-way swizzle both-sides. EPI 0 = FINAL
// (A3@WoT + b_out + x, grid 64x8); EPI 1 = LKV partials (vT@lkT slices,
// grid 32z x 16bx), replacing the old 2-barrier gemm_bt<PART>.
struct G1P {
  const unsigned short* A;
  const unsigned short* B;
  const float* bias;    // EPI 0
  const float* xres;    // EPI 0
  float* outF;          // EPI 0
  unsigned short* outU; // EPI 1: lkvP
};

template <int EPI>
__global__ __launch_bounds__(512, 4) void gemm128(G1P p) {
  extern __shared__ unsigned char lds[];   // 3 * 16384 = 49152 B dynamic
  const int tid  = threadIdx.x;
  const int lane = tid & 63;
  const int wave = tid >> 6;
  const int wm = (wave & 1) * 64;
  const int wn = (wave >> 1) * 32;
  const int lm = lane & 15;
  const int kb = lane >> 4;
  const int rA  = tid >> 2;                                    // 0..127
  const int kby = ((tid & 3) << 4) ^ (((rA >> 1) & 3) << 4);
  const int swz = kby >> 1;                                    // shorts
  const int fxor = (kb << 4) ^ (((lm >> 1) & 3) << 4);

  int bx, byz;
  const unsigned short* gA;
  const unsigned short* gB;
  if constexpr (EPI == 0) {
    bx  = blockIdx.x >> 3;          // 0..63 (m-tile of 8192)
    byz = blockIdx.x & 7;           // 0..7  (n-tile of 1024)
    gA = p.A + (long)(bx * 128 + rA) * 2048 + swz;
    gB = p.B + (long)(byz * 128 + rA) * 2048 + swz;
  } else {
    byz = blockIdx.x >> 4;          // z = 0..31 (b*8+s)
    bx  = blockIdx.x & 15;          // 0..15 (m-tile of 2048)
    const int b = byz >> 3, s = byz & 7;
    gA = p.A + (long)b * 4194304 + (long)(bx * 128 + rA) * 2048 + s * 256 + swz;
    gB = p.B + (long)b * 262144 + rA * 2048 + s * 256 + swz;
  }

  f32x4_t acc[4][2];
#pragma unroll
  for (int i = 0; i < 4; ++i)
#pragma unroll
    for (int j = 0; j < 2; ++j) acc[i][j] = (f32x4_t){0.f, 0.f, 0.f, 0.f};

  auto stage = [&](int t) {
    unsigned char* base = lds + (t % 3) * 16384;
    load_lds16(gA + t * 32, (unsigned short*)(base + wave * 1024));
    load_lds16(gB + t * 32, (unsigned short*)(base + 8192 + wave * 1024));
  };

  stage(0); stage(1);   // 4 loads in flight
  VMW(2);
  SBAR();

  constexpr int NT = (EPI == 0) ? 64 : 8;   // K=2048 / K=256
#pragma unroll 1
  for (int t = 0; t < NT; ++t) {
    const unsigned char* slot = lds + (t % 3) * 16384;
    bf16x8_t bF[2], aF[4];
#pragma unroll
    for (int j = 0; j < 2; ++j)
      bF[j] = *(const bf16x8_t*)(slot + 8192 + (wn + j * 16 + lm) * 64 + fxor);
#pragma unroll
    for (int i = 0; i < 4; ++i)
      aF[i] = *(const bf16x8_t*)(slot + (wm + i * 16 + lm) * 64 + fxor);
    if (t <= NT - 3) stage(t + 2);
    __builtin_amdgcn_s_setprio(1);
#pragma unroll
    for (int i = 0; i < 4; ++i)
#pragma unroll
      for (int j = 0; j < 2; ++j)
        acc[i][j] = __builtin_amdgcn_mfma_f32_16x16x32_bf16(aF[i], bF[j], acc[i][j], 0, 0, 0);
    __builtin_amdgcn_s_setprio(0);
    if (t <= NT - 3)      { VMW(2); }
    else if (t == NT - 2) { VMW(0); }
    SBAR();
  }

  // ---------------- epilogue ----------------
  if constexpr (EPI == 0) {
#pragma unroll
    for (int i = 0; i < 4; ++i) {
      const int row0 = bx * 128 + wm + i * 16 + (lane >> 4) * 4;
#pragma unroll
      for (int j = 0; j < 2; ++j) {
        const int col = byz * 128 + wn + j * 16 + lm;
        const float bb = p.bias[col];
#pragma unroll
        for (int r = 0; r < 4; ++r) {
          const long idx = (long)(row0 + r) * 1024 + col;
          p.outF[idx] = acc[i][j][r] + bb + p.xres[idx];
        }
      }
    }
  } else {
    unsigned short* slab = p.outU + (long)byz * 262144;
#pragma unroll
    for (int i = 0; i < 4; ++i) {
      const int row0 = bx * 128 + wm + i * 16 + (lane >> 4) * 4;
#pragma unroll
      for (int j = 0; j < 2; ++j) {
        const int col = wn + j * 16 + lm;
#pragma unroll
        for (int r = 0; r < 4; ++r)
          slab[(row0 + r) * 128 + col] = f2b(acc[i][j][r] * (1.0f / 2048.0f));
      }
    }
  }
}

// ---------------------------------------------------------------- GEMM (BT) 128^2 (ARELU only)
struct GemmP {
  const unsigned short* A;
  const unsigned short* B;
  int K, lda, ldb, ldc, mPerZ;
  long aZ, bZ;
  float scale;
  unsigned short* outU;
};

__global__ __launch_bounds__(256, 2) void gemm_arelu(GemmP p) {
  __shared__ __align__(16) unsigned char smem[16384];
  unsigned short* As = (unsigned short*)smem;             // [128][32] bf16
  unsigned short* Bs = (unsigned short*)(smem + 8192);    // [128][32] bf16

  const int tid = threadIdx.x;
  const int lane = tid & 63;
  const int wave = tid >> 6;
  const int bx = blockIdx.x;
  const int by = blockIdx.y;
  const int z = blockIdx.z;

  unsigned short* lA = As + wave * 32 * 32;
  unsigned short* lB = Bs + wave * 32 * 32;
  const int wm = (wave & 1) * 64;
  const int wn = (wave >> 1) * 64;
  const int lm = lane & 15;
  const int kb = lane >> 4;
  const int rowSel = (wave * 32 + (lane >> 2));   // staging row within 128-tile
  const int colSel = (lane & 3) * 8;              // staging k-offset

  f32x4_t acc[4][4];
#pragma unroll
  for (int i = 0; i < 4; ++i)
#pragma unroll
    for (int j = 0; j < 4; ++j) acc[i][j] = (f32x4_t){0.f, 0.f, 0.f, 0.f};

  const unsigned short* Ag = p.A + (long)z * p.aZ + (long)(bx * 128 + rowSel) * p.lda + colSel;
  const unsigned short* Bg = p.B + (long)z * p.bZ + (long)(by * 128 + rowSel) * p.ldb + colSel;
  const int a16 = 16 * p.lda, b16 = 16 * p.ldb;
  for (int kt = 0; kt < (p.K >> 5); ++kt) {
    load_lds16(Ag, lA);
    load_lds16(Ag + a16, lA + 512);
    load_lds16(Bg, lB);
    load_lds16(Bg + b16, lB + 512);
    Ag += 32; Bg += 32;
    __syncthreads();
    bf16x8_t aF[4], bF[4];
#pragma unroll
    for (int i = 0; i < 4; ++i)
      aF[i] = *(const bf16x8_t*)(As + (wm + i * 16 + lm) * 32 + kb * 8);
#pragma unroll
    for (int j = 0; j < 4; ++j)
      bF[j] = *(const bf16x8_t*)(Bs + (wn + j * 16 + lm) * 32 + kb * 8);
#pragma unroll
    for (int i = 0; i < 4; ++i)
#pragma unroll
      for (int j = 0; j < 4; ++j)
        acc[i][j] = __builtin_amdgcn_mfma_f32_16x16x32_bf16(aF[i], bF[j], acc[i][j], 0, 0, 0);
    __syncthreads();
  }

#pragma unroll
  for (int i = 0; i < 4; ++i) {
    const long rowg0 = (long)z * p.mPerZ + bx * 128 + wm + i * 16 + (lane >> 4) * 4;
#pragma unroll
    for (int j = 0; j < 4; ++j) {
      const int col = by * 128 + wn + j * 16 + lm;
#pragma unroll
      for (int r = 0; r < 4; ++r) {
        float s = acc[i][j][r] * p.scale;
        s = s > 0.f ? s : 0.f;
        p.outU[(rowg0 + r) * (long)p.ldc + col] = f2b(s * s);
      }
    }
  }
}

// ---------------------------------------------------------------- launch
extern "C" void kernel_launch(void* const* d_in, const int* in_sizes, int n_in,
                              void* d_out, int out_size, void* d_ws, size_t ws_size,
                              hipStream_t stream) {
  const float* x        = (const float*)d_in[0];
  const float* ln_g     = (const float*)d_in[1];
  const float* ln_b     = (const float*)d_in[2];
  const float* W_hidden = (const float*)d_in[3];
  const float* b_hidden = (const float*)d_in[4];
  const float* W_qk     = (const float*)d_in[5];
  const float* b_qk     = (const float*)d_in[6];
  const float* os_gamma = (const float*)d_in[7];
  const float* os_beta  = (const float*)d_in[8];
  const float* W_out    = (const float*)d_in[9];
  const float* b_out    = (const float*)d_in[10];
  float* out = (float*)d_out;

  char* w = (char*)d_ws;
  auto ws = [&](size_t bytes) { char* p = w; w += bytes; return (unsigned short*)p; };
  unsigned short* WT     = ws(8650752);   // [4224][1024] bf16 (Wh cols | Wqk cols)
  unsigned short* WoT    = ws(4194304);   // [1024][2048]
  unsigned short* normed = ws(16777216);  // [8192][1024]
  unsigned short* vT     = ws(33554432);  // [4][2048 e][2048 n]
  unsigned short* gate   = ws(33554432);  // [8192][2048]
  unsigned short* qq     = ws(2097152);
  unsigned short* qkh    = ws(2097152);
  unsigned short* lq     = ws(2097152);
  unsigned short* lkT    = ws(2097152);   // [4][128][2048]
  unsigned short* attn   = ws(4194304);   // [32][256][256]
  unsigned short* lkvP   = ws(16777216);  // [32 slabs][2048][128] bf16 partials
  unsigned short* lkvT   = ws(2097152);   // [4][2048 e][128 d] bf16
  unsigned short* A3     = ws(33554432);  // [8192][2048]

  static bool s_attr = false;
  if (!s_attr) {
    hipFuncSetAttribute((const void*)gemm8p,
                        hipFuncAttributeMaxDynamicSharedMemorySize, 73728);
    hipFuncSetAttribute((const void*)gemmQL,
                        hipFuncAttributeMaxDynamicSharedMemorySize, 73728);
    hipFuncSetAttribute((const void*)gemm128<0>,
                        hipFuncAttributeMaxDynamicSharedMemorySize, 49152);
    hipFuncSetAttribute((const void*)gemm128<1>,
                        hipFuncAttributeMaxDynamicSharedMemorySize, 49152);
    s_attr = true;
  }

  {  // weight transposes + layernorm in one dispatch
    PrepP p{W_hidden, W_out, W_qk, x, ln_g, ln_b, WT, WoT, normed};
    prep_kernel<<<14464, 256, 0, stream>>>(p);
  }
  {  // GEMM1: qk (blocks 0..31, dispatched first) + v->vT | gate (32..1055)
    G8P p{normed, WT, b_hidden, b_qk, os_gamma, os_beta,
          vT, gate, qq, lq, qkh, lkT};
    gemm8p<<<dim3(1056, 1, 1), 512, 73728, stream>>>(p);
  }
  {  // sim -> attn = relu(sim/256)^2, per (b,g)
    GemmP p{}; p.A = qq; p.B = qkh; p.K = 128; p.lda = 128; p.ldb = 128;
    p.ldc = 256; p.mPerZ = 256; p.aZ = 32768; p.bZ = 32768;
    p.scale = 1.f / 256.f; p.outU = attn;
    gemm_arelu<<<dim3(2, 2, 32), 256, 0, stream>>>(p);
  }
  {  // lin_kv partials: slab[z=b*8+s][e][d] = vT[b][e][sK] @ lkT[b][d][sK] / 2048
    G1P p{}; p.A = vT; p.B = lkT; p.outU = lkvP;
    gemm128<1><<<dim3(512, 1, 1), 512, 49152, stream>>>(p);
  }
  reduce_cvt<<<1024, 256, 0, stream>>>(lkvP, lkvT);
  {  // A3 = gate * (attn @ vg + lin_q @ lin_kv)   (3-slot ring, 2 blocks/CU)
    GQLP p{attn, vT, lq, lkvT, gate, A3};
    gemmQL<<<dim3(512, 1, 1), 512, 73728, stream>>>(p);
  }
  {  // out = A3 @ W_out + b_out + x  (128^2 pipelined, 512 blocks, 2/CU)
    G1P p{}; p.A = A3; p.B = WoT; p.bias = b_out; p.xres = x; p.outF = out;
    gemm128<0><<<dim3(512, 1, 1), 512, 49152, stream>>>(p);
  }
}

// Round 9
// 301.786 us; speedup vs baseline: 1.0106x; 1.0106x over previous
//
#include <hip/hip_runtime.h>
#include <stdint.h>

typedef __attribute__((ext_vector_type(8))) short bf16x8_t;   // 8 bf16 in 4 VGPRs
typedef __attribute__((ext_vector_type(4))) float f32x4_t;

#define DI __device__ __forceinline__
#define SBAR() asm volatile("s_barrier" ::: "memory")
#define VMW(n) asm volatile("s_waitcnt vmcnt(" #n ")" ::: "memory")

DI unsigned short f2b(float f) {
  union { float f; unsigned int u; } c; c.f = f;
  unsigned int u = c.u + 0x7FFFu + ((c.u >> 16) & 1u);   // RNE
  return (unsigned short)(u >> 16);
}
DI unsigned int pack2(float lo, float hi) {
  return (unsigned int)f2b(lo) | ((unsigned int)f2b(hi) << 16);
}
DI float b2f(unsigned short h) {
  union { unsigned int u; float f; } c; c.u = ((unsigned int)h) << 16;
  return c.f;
}
DI float silu_f(float z) { return z / (1.0f + __expf(-z)); }

// async global->LDS, 16B per lane; LDS dst = wave-uniform base + lane*16B
DI void load_lds16(const unsigned short* g, unsigned short* l) {
  __builtin_amdgcn_global_load_lds(
      (const __attribute__((address_space(1))) unsigned int*)g,
      (__attribute__((address_space(3))) unsigned int*)l,
      16, 0, 0);
}

// ---------------------------------------------------------------- prep mega-kernel
struct PrepP {
  const float *Wh, *Wo, *Wqk, *x, *g, *b;
  unsigned short *WT, *WoT, *normed;
};

__global__ __launch_bounds__(256) void prep_kernel(PrepP p) {
  const int blk = blockIdx.x;
  const int tx = threadIdx.x & 31, ty = threadIdx.x >> 5;
  if (blk < 6272) {
    const float* in; unsigned short* out; int R, C, gx;
    if (blk < 4096)      { in = p.Wh;  out = p.WT;                 R = 1024; C = 4096; gx = blk; }
    else if (blk < 6144) { in = p.Wo;  out = p.WoT;                R = 2048; C = 1024; gx = blk - 4096; }
    else                 { in = p.Wqk; out = p.WT + 4096 * 1024;   R = 1024; C = 128;  gx = blk - 6144; }
    const int xTiles = C >> 5;
    const int c0 = (gx % xTiles) * 32, r0 = (gx / xTiles) * 32;
    __shared__ float tile[32][33];
#pragma unroll
    for (int i = 0; i < 4; ++i)
      tile[ty + 8 * i][tx] = in[(long)(r0 + ty + 8 * i) * C + c0 + tx];
    __syncthreads();
#pragma unroll
    for (int i = 0; i < 4; ++i)
      out[(long)(c0 + ty + 8 * i) * R + r0 + tx] = f2b(tile[tx][ty + 8 * i]);
  } else {
    const int row = blk - 6272, tid = threadIdx.x;
    __shared__ float red[8];
    float4 v = ((const float4*)(p.x + (long)row * 1024))[tid];
    float s = v.x + v.y + v.z + v.w;
    float ss = v.x * v.x + v.y * v.y + v.z * v.z + v.w * v.w;
    for (int o = 32; o > 0; o >>= 1) { s += __shfl_down(s, o); ss += __shfl_down(ss, o); }
    const int wave = tid >> 6, lane = tid & 63;
    if (lane == 0) { red[wave * 2] = s; red[wave * 2 + 1] = ss; }
    __syncthreads();
    if (tid == 0) {
      float S = red[0] + red[2] + red[4] + red[6];
      float SS = red[1] + red[3] + red[5] + red[7];
      float mu = S * (1.0f / 1024.0f);
      float var = SS * (1.0f / 1024.0f) - mu * mu;
      red[0] = mu; red[1] = rsqrtf(var + 1e-5f);
    }
    __syncthreads();
    const float mu = red[0], rstd = red[1];
    float4 gg = ((const float4*)p.g)[tid];
    float4 bb = ((const float4*)p.b)[tid];
    ushort4 o;
    o.x = f2b((v.x - mu) * rstd * gg.x + bb.x);
    o.y = f2b((v.y - mu) * rstd * gg.y + bb.y);
    o.z = f2b((v.z - mu) * rstd * gg.z + bb.z);
    o.w = f2b((v.w - mu) * rstd * gg.w + bb.w);
    ((ushort4*)(p.normed + (long)row * 1024))[tid] = o;
  }
}

// ---------------------------------------------------------------- reduce 8 bf16 slabs -> bf16
__global__ __launch_bounds__(256) void reduce_cvt(
    const unsigned short* __restrict__ part, unsigned short* __restrict__ out) {
  const int idx = blockIdx.x * 256 + threadIdx.x;
  const int b = idx >> 16, i = idx & 65535;
  float4 s = make_float4(0.f, 0.f, 0.f, 0.f);
#pragma unroll
  for (int sl = 0; sl < 8; ++sl) {
    ushort4 v = ((const ushort4*)part)[(long)(b * 8 + sl) * 65536 + i];
    s.x += b2f(v.x); s.y += b2f(v.y); s.z += b2f(v.z); s.w += b2f(v.w);
  }
  ushort4 o;
  o.x = f2b(s.x); o.y = f2b(s.y); o.z = f2b(s.z); o.w = f2b(s.w);
  ((ushort4*)out)[(long)b * 65536 + i] = o;
}

// ---------------------------------------------------------------- 8-wave 256x128 deep-pipelined GEMM1
// R10 (proven): 3-slot/2-blocks-per-CU geometry, counted VMW(3)/0, 1 SBAR/tile.
struct G8P {
  const unsigned short* A;
  const unsigned short* B;
  const float* bias;          // b_hidden[4096]
  const float* bias2;         // b_qk[128]
  const float* gamma;         // os_gamma [4][128]
  const float* beta;          // os_beta  [4][128]
  unsigned short* vTout;      // [4][2048 e][2048 n]
  unsigned short* gateOut;    // [8192][2048]
  unsigned short* qqO;        // [8192][128]
  unsigned short* lqO;
  unsigned short* qkhO;
  unsigned short* lkTO;       // [4][128][2048]
};

__global__ __launch_bounds__(512, 4) void gemm8p(G8P p) {
  extern __shared__ unsigned char lds[];   // 3 * 24576 = 73728 B dynamic
  const int tid  = threadIdx.x;
  const int lane = tid & 63;
  const int wave = tid >> 6;
  const bool qk = blockIdx.x < 32;
  int bx, by;
  if (qk) { bx = blockIdx.x; by = 32; }                 // B rows 4096..4223
  else    { const int vg = blockIdx.x - 32; bx = vg >> 5; by = vg & 31; }
  const int wm = (wave & 1) * 128;
  const int wn = (wave >> 1) * 32;
  const int lm = lane & 15;
  const int kb = lane >> 4;

  // ---- staging coords (pre-swizzled global source; LDS lands linear) ----
  const int rA  = tid >> 2;                                    // 0..127
  const int kby = ((tid & 3) << 4) ^ (((rA >> 1) & 3) << 4);   // 2-way swizzle
  const unsigned short* gA0 = p.A + (long)(bx * 256 + rA) * 1024 + (kby >> 1);
  const unsigned short* gA1 = gA0 + 128 * 1024;
  const int brow = qk ? 4096 : by * 128;
  const unsigned short* gB0 = p.B + (long)(brow + rA) * 1024 + (kby >> 1);

  // ---- fragment-read lane constant ((row>>1)&3 == (lm>>1)&3 for all reps) ----
  const int fxor = (kb << 4) ^ (((lm >> 1) & 3) << 4);

  f32x4_t acc[8][2];
#pragma unroll
  for (int i = 0; i < 8; ++i)
#pragma unroll
    for (int j = 0; j < 2; ++j) acc[i][j] = (f32x4_t){0.f, 0.f, 0.f, 0.f};

  auto stageA = [&](int t) {
    unsigned short* l = (unsigned short*)(lds + (t % 3) * 24576 + wave * 1024);
    load_lds16(gA0 + t * 32, l);
    load_lds16(gA1 + t * 32, (unsigned short*)((unsigned char*)l + 8192));
  };
  auto stageB = [&](int t) {   // 128 rows x 64B = 8KB = 1 load/thread
    unsigned short* l = (unsigned short*)(lds + (t % 3) * 24576 + 16384 + wave * 1024);
    load_lds16(gB0 + t * 32, l);
  };

  // prologue: 2 tiles in flight (6 loads/thread)
#pragma unroll
  for (int u = 0; u < 2; ++u) { stageA(u); stageB(u); }
  VMW(3);
  SBAR();

  constexpr int NT = 16;   // K=1024 / BK=32
#pragma unroll 1
  for (int t = 0; t < NT; ++t) {
    const unsigned char* slot = lds + (t % 3) * 24576;
    bf16x8_t bF[2], aF[4];
#pragma unroll
    for (int j = 0; j < 2; ++j)
      bF[j] = *(const bf16x8_t*)(slot + 16384 + (wn + j * 16 + lm) * 64 + fxor);
#pragma unroll
    for (int i = 0; i < 4; ++i)
      aF[i] = *(const bf16x8_t*)(slot + (wm + i * 16 + lm) * 64 + fxor);
    if (t <= NT - 3) stageA(t + 2);
    __builtin_amdgcn_s_setprio(1);
#pragma unroll
    for (int i = 0; i < 4; ++i)
#pragma unroll
      for (int j = 0; j < 2; ++j)
        acc[i][j] = __builtin_amdgcn_mfma_f32_16x16x32_bf16(aF[i], bF[j], acc[i][j], 0, 0, 0);
    __builtin_amdgcn_s_setprio(0);
#pragma unroll
    for (int i = 0; i < 4; ++i)
      aF[i] = *(const bf16x8_t*)(slot + (wm + 64 + i * 16 + lm) * 64 + fxor);
    if (t <= NT - 3) stageB(t + 2);
    __builtin_amdgcn_s_setprio(1);
#pragma unroll
    for (int i = 0; i < 4; ++i)
#pragma unroll
      for (int j = 0; j < 2; ++j)
        acc[i + 4][j] = __builtin_amdgcn_mfma_f32_16x16x32_bf16(aF[i], bF[j], acc[i + 4][j], 0, 0, 0);
    __builtin_amdgcn_s_setprio(0);
    if (t <= NT - 3)      { VMW(3); }
    else if (t == NT - 2) { VMW(0); }
    SBAR();   // single barrier per tile
  }

  // ---------------- epilogue ----------------
  if (qk) {
    // silu -> LDS [256][136] -> OffsetScale+RoPE. All 8 waves write (BN=128).
    unsigned short* q16 = (unsigned short*)lds;   // 69632 B <= 73728
#pragma unroll
    for (int i = 0; i < 8; ++i) {
      const int rloc = wm + i * 16 + (lane >> 4) * 4;   // 0..255
#pragma unroll
      for (int j = 0; j < 2; ++j) {
        const int cl = wn + j * 16 + lm;                // 0..127
        const float bb = p.bias2[cl];
#pragma unroll
        for (int r = 0; r < 4; ++r)
          q16[(rloc + r) * 136 + cl] = f2b(silu_f(acc[i][j][r] + bb));
      }
    }
    __syncthreads();
    const int j = tid & 63;
    const int rq = tid >> 6;                              // 0..7
    const float freq = powf(10000.0f, (float)j * (1.0f / 64.0f));
    float ga[4], gb[4], ea[4], eb[4];
#pragma unroll
    for (int h = 0; h < 4; ++h) {
      ga[h] = p.gamma[h * 128 + j];  gb[h] = p.gamma[h * 128 + 64 + j];
      ea[h] = p.beta[h * 128 + j];   eb[h] = p.beta[h * 128 + 64 + j];
    }
    unsigned short* outs[3] = {p.qqO, p.lqO, p.qkhO};
    for (int rr = 0; rr < 32; ++rr) {
      const int row = rr * 8 + rq;                        // 0..255
      const float x1 = b2f(q16[row * 136 + j]);
      const float x2 = b2f(q16[row * 136 + 64 + j]);
      const int tok = bx * 256 + row;
      const int pos = tok & 2047, bidx = tok >> 11;
      const float ang = (float)pos * freq;
      const float sn = sinf(ang), cs = cosf(ang);
#pragma unroll
      for (int h = 0; h < 3; ++h) {
        const float y1 = x1 * ga[h] + ea[h], y2 = x2 * gb[h] + eb[h];
        outs[h][(long)tok * 128 + j] = f2b(y1 * cs - y2 * sn);
        outs[h][(long)tok * 128 + 64 + j] = f2b(y2 * cs + y1 * sn);
      }
      const float y1 = x1 * ga[3] + ea[3], y2 = x2 * gb[3] + eb[3];
      p.lkTO[((long)bidx * 128 + j) * 2048 + pos] = f2b(y1 * cs - y2 * sn);
      p.lkTO[((long)bidx * 128 + 64 + j) * 2048 + pos] = f2b(y2 * cs + y1 * sn);
    }
  } else if (by < 16) {
    // v half: silu+bias, pack pairs, 256x128 transpose via [128][128]-uint LDS
    // (64KB), chunk-XOR (e&7) kills conflicts; coalesced 512B vT row stores.
    unsigned int* Cx = (unsigned int*)lds;
#pragma unroll
    for (int i = 0; i < 8; ++i) {
      const int c0 = (wm + i * 16) / 2 + (lane >> 4) * 2;   // even uint col 0..127
#pragma unroll
      for (int j = 0; j < 2; ++j) {
        const int e = wn + j * 16 + lm;                     // 0..127
        const float bb = p.bias[by * 128 + e];
        const float s0 = silu_f(acc[i][j][0] + bb);
        const float s1 = silu_f(acc[i][j][1] + bb);
        const float s2 = silu_f(acc[i][j][2] + bb);
        const float s3 = silu_f(acc[i][j][3] + bb);
        const int x = (e & 7) << 2;
        Cx[e * 128 + (c0 ^ x)]     = pack2(s0, s1);
        Cx[e * 128 + (c0 ^ x) + 1] = pack2(s2, s3);
      }
    }
    __syncthreads();
    const int bq = bx >> 3, nloc0 = (bx & 7) * 256, e0g = by * 128;
    unsigned short* dstBase = p.vTout + ((long)(bq * 2048 + e0g)) * 2048 + nloc0;
#pragma unroll
    for (int rep = 0; rep < 8; ++rep) {
      const int flat = rep * 512 + tid;
      const int e = flat >> 5, q = flat & 31;
      uint4 val = *(const uint4*)(Cx + e * 128 + ((q ^ (e & 7)) << 2));
      *(uint4*)(dstBase + (long)e * 2048 + q * 8) = val;
    }
  } else {
    // gate half: cols 2048 + (by-16)*128 ..
#pragma unroll
    for (int i = 0; i < 8; ++i) {
      const int row0 = bx * 256 + wm + i * 16 + (lane >> 4) * 4;
#pragma unroll
      for (int j = 0; j < 2; ++j) {
        const int colg = (by - 16) * 128 + wn + j * 16 + lm;   // 0..2047
        const float bb = p.bias[2048 + colg];
#pragma unroll
        for (int r = 0; r < 4; ++r)
          p.gateOut[(long)(row0 + r) * 2048 + colg] =
              f2b(silu_f(acc[i][j][r] + bb));
      }
    }
  }
}

// ---------------------------------------------------------------- QUADLIN: A3 = gate*(attn@vg + lq@lkv)
struct GQLP {
  const unsigned short* attn;   // [32][256][256]
  const unsigned short* vT;     // [4][2048][2048]
  const unsigned short* lq;     // [8192][128]
  const unsigned short* lkvT;   // [4][2048][128]
  const unsigned short* gateIn; // [8192][2048]
  unsigned short* outU;         // A3 [8192][2048]
};

__global__ __launch_bounds__(512, 4) void gemmQL(GQLP p) {
  extern __shared__ unsigned char lds[];   // 3 * 24576 = 73728 B dynamic
  const int tid  = threadIdx.x;
  const int lane = tid & 63;
  const int wave = tid >> 6;
  const int z  = blockIdx.x >> 4;    // 0..31 (b*8+g)
  const int by = blockIdx.x & 15;    // 0..15 (n-tile of 2048, 128 wide)
  const int b = z >> 3, g = z & 7;
  const int wm = (wave & 1) * 128;
  const int wn = (wave >> 1) * 32;
  const int lm = lane & 15;
  const int kb = lane >> 4;

  const int rA  = tid >> 2;                                    // 0..127
  const int kby = ((tid & 3) << 4) ^ (((rA >> 1) & 3) << 4);
  const int swz = kby >> 1;                                    // shorts
  const unsigned short* a1 = p.attn + (long)z * 65536 + rA * 256 + swz;
  const unsigned short* a2 = p.lq + ((long)z * 256 + rA) * 128 + swz;
  const unsigned short* b1 = p.vT + (long)b * 4194304 + (long)(by * 128 + rA) * 2048 + g * 256 + swz;
  const unsigned short* b2 = p.lkvT + (long)b * 262144 + (by * 128 + rA) * 128 + swz;
  const int fxor = (kb << 4) ^ (((lm >> 1) & 3) << 4);

  f32x4_t acc[8][2];
#pragma unroll
  for (int i = 0; i < 8; ++i)
#pragma unroll
    for (int j = 0; j < 2; ++j) acc[i][j] = (f32x4_t){0.f, 0.f, 0.f, 0.f};

  auto stageA = [&](int tt) {
    unsigned char* base = lds + (tt % 3) * 24576;
    unsigned short* l  = (unsigned short*)(base + wave * 1024);
    unsigned short* lh = (unsigned short*)(base + wave * 1024 + 8192);
    if (tt < 8) { load_lds16(a1 + tt * 32, l); load_lds16(a1 + 128 * 256 + tt * 32, lh); }
    else { const int k2 = (tt - 8) * 32;
           load_lds16(a2 + k2, l); load_lds16(a2 + 128 * 128 + k2, lh); }
  };
  auto stageB = [&](int tt) {   // 128 rows x 64B = 8KB = 1 load/thread
    unsigned short* l = (unsigned short*)(lds + (tt % 3) * 24576 + 16384 + wave * 1024);
    if (tt < 8) load_lds16(b1 + tt * 32, l);
    else        load_lds16(b2 + (tt - 8) * 32, l);
  };

#pragma unroll
  for (int u = 0; u < 2; ++u) { stageA(u); stageB(u); }   // 6 in flight
  VMW(3);
  SBAR();

  constexpr int NT = 12;   // 8 (K=256 phase1) + 4 (K=128 phase2)
#pragma unroll 1
  for (int t = 0; t < NT; ++t) {
    const unsigned char* slot = lds + (t % 3) * 24576;
    bf16x8_t bF[2], aF[4];
#pragma unroll
    for (int j = 0; j < 2; ++j)
      bF[j] = *(const bf16x8_t*)(slot + 16384 + (wn + j * 16 + lm) * 64 + fxor);
#pragma unroll
    for (int i = 0; i < 4; ++i)
      aF[i] = *(const bf16x8_t*)(slot + (wm + i * 16 + lm) * 64 + fxor);
    if (t <= NT - 3) stageA(t + 2);
    __builtin_amdgcn_s_setprio(1);
#pragma unroll
    for (int i = 0; i < 4; ++i)
#pragma unroll
      for (int j = 0; j < 2; ++j)
        acc[i][j] = __builtin_amdgcn_mfma_f32_16x16x32_bf16(aF[i], bF[j], acc[i][j], 0, 0, 0);
    __builtin_amdgcn_s_setprio(0);
#pragma unroll
    for (int i = 0; i < 4; ++i)
      aF[i] = *(const bf16x8_t*)(slot + (wm + 64 + i * 16 + lm) * 64 + fxor);
    if (t <= NT - 3) stageB(t + 2);
    __builtin_amdgcn_s_setprio(1);
#pragma unroll
    for (int i = 0; i < 4; ++i)
#pragma unroll
      for (int j = 0; j < 2; ++j)
        acc[i + 4][j] = __builtin_amdgcn_mfma_f32_16x16x32_bf16(aF[i], bF[j], acc[i + 4][j], 0, 0, 0);
    __builtin_amdgcn_s_setprio(0);
    if (t <= NT - 3)      { VMW(3); }
    else if (t == NT - 2) { VMW(0); }
    SBAR();
  }

  // epilogue: A3 = gate * acc
#pragma unroll
  for (int i = 0; i < 8; ++i) {
    const int row0 = z * 256 + wm + i * 16 + (lane >> 4) * 4;
#pragma unroll
    for (int j = 0; j < 2; ++j) {
      const int col = by * 128 + wn + j * 16 + lm;
#pragma unroll
      for (int r = 0; r < 4; ++r) {
        const long idx = (long)(row0 + r) * 2048 + col;
        p.outU[idx] = f2b(b2f(p.gateIn[idx]) * acc[i][j][r]);
      }
    }
  }
}

// ---------------------------------------------------------------- FINAL: A3 @ WoT + b_out + x
// R12: restored R10's proven 4-slot 98KB version (R11's 128^2 port regressed:
// 8 MFMA/barrier can't amortize the per-tile sync; 6 ds_read > MFMA window).
struct GWoP {
  const unsigned short* A;   // A3 [8192][2048]
  const unsigned short* B;   // WoT [1024][2048]
  const float* bias;         // b_out[1024]
  const float* xres;         // x fp32 [8192][1024]
  float* outF;               // [8192][1024]
};

__global__ __launch_bounds__(512, 2) void gemmWo(GWoP p) {
  extern __shared__ unsigned char lds[];   // 4 * 24576 = 98304 B dynamic
  const int tid  = threadIdx.x;
  const int lane = tid & 63;
  const int wave = tid >> 6;
  const int bx = blockIdx.x >> 3;          // 0..31 (m-tile, 256 rows)
  const int by = blockIdx.x & 7;           // 0..7  (n-tile, 128 cols)
  const int wm = (wave & 1) * 128;
  const int wn = (wave >> 1) * 32;         // 4 n-groups of 32
  const int lm = lane & 15;
  const int kb = lane >> 4;

  const int rA  = tid >> 2;                                    // 0..127
  const int kby = ((tid & 3) << 4) ^ (((rA >> 1) & 3) << 4);
  const unsigned short* gA0 = p.A + (long)(bx * 256 + rA) * 2048 + (kby >> 1);
  const unsigned short* gA1 = gA0 + 128 * 2048;
  const unsigned short* gB0 = p.B + (long)(by * 128 + rA) * 2048 + (kby >> 1);
  const int fxor = (kb << 4) ^ (((lm >> 1) & 3) << 4);

  f32x4_t acc[8][2];
#pragma unroll
  for (int i = 0; i < 8; ++i)
#pragma unroll
    for (int j = 0; j < 2; ++j) acc[i][j] = (f32x4_t){0.f, 0.f, 0.f, 0.f};

  auto stageA = [&](int t) {
    unsigned short* l = (unsigned short*)(lds + (t & 3) * 24576 + wave * 1024);
    load_lds16(gA0 + t * 32, l);
    load_lds16(gA1 + t * 32, (unsigned short*)((unsigned char*)l + 8192));
  };
  auto stageB = [&](int t) {   // 128 rows x 64B = 8KB = 1 load/thread
    unsigned short* l = (unsigned short*)(lds + (t & 3) * 24576 + 16384 + wave * 1024);
    load_lds16(gB0 + t * 32, l);
  };

#pragma unroll
  for (int u = 0; u < 3; ++u) { stageA(u); stageB(u); }   // 9 in flight
  VMW(6);
  SBAR();

  constexpr int NT = 64;   // K=2048 / BK=32
#pragma unroll 1
  for (int t = 0; t < NT; ++t) {
    const unsigned char* slot = lds + (t & 3) * 24576;
    bf16x8_t bF[2], aF[4];
#pragma unroll
    for (int j = 0; j < 2; ++j)
      bF[j] = *(const bf16x8_t*)(slot + 16384 + (wn + j * 16 + lm) * 64 + fxor);
#pragma unroll
    for (int i = 0; i < 4; ++i)
      aF[i] = *(const bf16x8_t*)(slot + (wm + i * 16 + lm) * 64 + fxor);
    if (t <= NT - 4) stageA(t + 3);
    __builtin_amdgcn_s_setprio(1);
#pragma unroll
    for (int i = 0; i < 4; ++i)
#pragma unroll
      for (int j = 0; j < 2; ++j)
        acc[i][j] = __builtin_amdgcn_mfma_f32_16x16x32_bf16(aF[i], bF[j], acc[i][j], 0, 0, 0);
    __builtin_amdgcn_s_setprio(0);
#pragma unroll
    for (int i = 0; i < 4; ++i)
      aF[i] = *(const bf16x8_t*)(slot + (wm + 64 + i * 16 + lm) * 64 + fxor);
    if (t <= NT - 4) stageB(t + 3);
    __builtin_amdgcn_s_setprio(1);
#pragma unroll
    for (int i = 0; i < 4; ++i)
#pragma unroll
      for (int j = 0; j < 2; ++j)
        acc[i + 4][j] = __builtin_amdgcn_mfma_f32_16x16x32_bf16(aF[i], bF[j], acc[i + 4][j], 0, 0, 0);
    __builtin_amdgcn_s_setprio(0);
    if (t <= NT - 4)      { VMW(6); }
    else if (t == NT - 3) { VMW(3); }
    else if (t == NT - 2) { VMW(0); }
    SBAR();
  }

  // epilogue: + bias + x residual, fp32 out
#pragma unroll
  for (int i = 0; i < 8; ++i) {
    const int row0 = bx * 256 + wm + i * 16 + (lane >> 4) * 4;
#pragma unroll
    for (int j = 0; j < 2; ++j) {
      const int col = by * 128 + wn + j * 16 + lm;
      const float bb = p.bias[col];
#pragma unroll
      for (int r = 0; r < 4; ++r) {
        const long idx = (long)(row0 + r) * 1024 + col;
        p.outF[idx] = acc[i][j][r] + bb + p.xres[idx];
      }
    }
  }
}

// ---------------------------------------------------------------- merged ARELU + LKV-PART dispatch
// R12: ARELU (128 blocks) and PART (512 blocks) are mutually independent —
// both consume only gemm8p outputs and write disjoint buffers — but ARELU as
// its own dispatch ran at half-GPU occupancy. One 640-block dispatch: blocks
// 0..511 = PART (lkv partial slabs), 512..639 = ARELU (attn=relu^2(qq@qkh/256)).
// Same legacy 4-wave K-loop for both branches (runtime lda/ksteps).
struct GAPP {
  const unsigned short* vT;    // [4][2048][2048]
  const unsigned short* lkT;   // [4][128][2048]
  unsigned short* lkvP;        // [32 slabs][2048][128]
  const unsigned short* qq;    // [8192][128]
  const unsigned short* qkh;   // [8192][128]
  unsigned short* attn;        // [32][256][256]
};

__global__ __launch_bounds__(256, 2) void gemm_ap(GAPP p) {
  __shared__ __align__(16) unsigned char smem[16384];
  unsigned short* As = (unsigned short*)smem;             // [128][32] bf16
  unsigned short* Bs = (unsigned short*)(smem + 8192);    // [128][32] bf16

  const int tid = threadIdx.x;
  const int lane = tid & 63;
  const int wave = tid >> 6;
  const bool isPart = blockIdx.x < 512;

  unsigned short* lA = As + wave * 32 * 32;
  unsigned short* lB = Bs + wave * 32 * 32;
  const int wm = (wave & 1) * 64;
  const int wn = (wave >> 1) * 64;
  const int lm = lane & 15;
  const int kb = lane >> 4;
  const int rowSel = (wave * 32 + (lane >> 2));   // staging row within 128-tile
  const int colSel = (lane & 3) * 8;              // staging k-offset

  const unsigned short* Ag;
  const unsigned short* Bg;
  int lda, ldb, ksteps;
  int zi, bxi, byi;
  if (isPart) {
    zi  = blockIdx.x >> 4;             // 0..31 (b*8+s)
    bxi = blockIdx.x & 15;             // m-tile of 2048
    byi = 0;
    const int b = zi >> 3, s = zi & 7;
    Ag = p.vT + (long)b * 4194304 + (long)(bxi * 128 + rowSel) * 2048 + s * 256 + colSel;
    Bg = p.lkT + (long)b * 262144 + (long)rowSel * 2048 + s * 256 + colSel;
    lda = 2048; ldb = 2048; ksteps = 8;   // K=256
  } else {
    const int a = blockIdx.x - 512;    // 0..127
    zi  = a >> 2;                      // 0..31
    bxi = (a >> 1) & 1;
    byi = a & 1;
    Ag = p.qq  + ((long)zi * 256 + bxi * 128 + rowSel) * 128 + colSel;
    Bg = p.qkh + ((long)zi * 256 + byi * 128 + rowSel) * 128 + colSel;
    lda = 128; ldb = 128; ksteps = 4;     // K=128
  }

  f32x4_t acc[4][4];
#pragma unroll
  for (int i = 0; i < 4; ++i)
#pragma unroll
    for (int j = 0; j < 4; ++j) acc[i][j] = (f32x4_t){0.f, 0.f, 0.f, 0.f};

  const int a16 = 16 * lda, b16 = 16 * ldb;
  for (int kt = 0; kt < ksteps; ++kt) {
    load_lds16(Ag, lA);
    load_lds16(Ag + a16, lA + 512);
    load_lds16(Bg, lB);
    load_lds16(Bg + b16, lB + 512);
    Ag += 32; Bg += 32;
    __syncthreads();
    bf16x8_t aF[4], bF[4];
#pragma unroll
    for (int i = 0; i < 4; ++i)
      aF[i] = *(const bf16x8_t*)(As + (wm + i * 16 + lm) * 32 + kb * 8);
#pragma unroll
    for (int j = 0; j < 4; ++j)
      bF[j] = *(const bf16x8_t*)(Bs + (wn + j * 16 + lm) * 32 + kb * 8);
#pragma unroll
    for (int i = 0; i < 4; ++i)
#pragma unroll
      for (int j = 0; j < 4; ++j)
        acc[i][j] = __builtin_amdgcn_mfma_f32_16x16x32_bf16(aF[i], bF[j], acc[i][j], 0, 0, 0);
    __syncthreads();
  }

  if (isPart) {
    unsigned short* slab = p.lkvP + (long)zi * 262144;
#pragma unroll
    for (int i = 0; i < 4; ++i) {
      const int row0 = bxi * 128 + wm + i * 16 + (lane >> 4) * 4;
#pragma unroll
      for (int j = 0; j < 4; ++j) {
        const int col = wn + j * 16 + lm;   // 0..127
#pragma unroll
        for (int r = 0; r < 4; ++r)
          slab[(row0 + r) * 128 + col] = f2b(acc[i][j][r] * (1.0f / 2048.0f));
      }
    }
  } else {
    unsigned short* outA = p.attn + (long)zi * 65536;
#pragma unroll
    for (int i = 0; i < 4; ++i) {
      const int row0 = bxi * 128 + wm + i * 16 + (lane >> 4) * 4;
#pragma unroll
      for (int j = 0; j < 4; ++j) {
        const int col = byi * 128 + wn + j * 16 + lm;
#pragma unroll
        for (int r = 0; r < 4; ++r) {
          float s = acc[i][j][r] * (1.0f / 256.0f);
          s = s > 0.f ? s : 0.f;
          outA[(row0 + r) * 256 + col] = f2b(s * s);
        }
      }
    }
  }
}

// ---------------------------------------------------------------- launch
extern "C" void kernel_launch(void* const* d_in, const int* in_sizes, int n_in,
                              void* d_out, int out_size, void* d_ws, size_t ws_size,
                              hipStream_t stream) {
  const float* x        = (const float*)d_in[0];
  const float* ln_g     = (const float*)d_in[1];
  const float* ln_b     = (const float*)d_in[2];
  const float* W_hidden = (const float*)d_in[3];
  const float* b_hidden = (const float*)d_in[4];
  const float* W_qk     = (const float*)d_in[5];
  const float* b_qk     = (const float*)d_in[6];
  const float* os_gamma = (const float*)d_in[7];
  const float* os_beta  = (const float*)d_in[8];
  const float* W_out    = (const float*)d_in[9];
  const float* b_out    = (const float*)d_in[10];
  float* out = (float*)d_out;

  char* w = (char*)d_ws;
  auto ws = [&](size_t bytes) { char* p = w; w += bytes; return (unsigned short*)p; };
  unsigned short* WT     = ws(8650752);   // [4224][1024] bf16 (Wh cols | Wqk cols)
  unsigned short* WoT    = ws(4194304);   // [1024][2048]
  unsigned short* normed = ws(16777216);  // [8192][1024]
  unsigned short* vT     = ws(33554432);  // [4][2048 e][2048 n]
  unsigned short* gate   = ws(33554432);  // [8192][2048]
  unsigned short* qq     = ws(2097152);
  unsigned short* qkh    = ws(2097152);
  unsigned short* lq     = ws(2097152);
  unsigned short* lkT    = ws(2097152);   // [4][128][2048]
  unsigned short* attn   = ws(4194304);   // [32][256][256]
  unsigned short* lkvP   = ws(16777216);  // [32 slabs][2048][128] bf16 partials
  unsigned short* lkvT   = ws(2097152);   // [4][2048 e][128 d] bf16
  unsigned short* A3     = ws(33554432);  // [8192][2048]

  static bool s_attr = false;
  if (!s_attr) {
    hipFuncSetAttribute((const void*)gemm8p,
                        hipFuncAttributeMaxDynamicSharedMemorySize, 73728);
    hipFuncSetAttribute((const void*)gemmQL,
                        hipFuncAttributeMaxDynamicSharedMemorySize, 73728);
    hipFuncSetAttribute((const void*)gemmWo,
                        hipFuncAttributeMaxDynamicSharedMemorySize, 98304);
    s_attr = true;
  }

  {  // weight transposes + layernorm in one dispatch
    PrepP p{W_hidden, W_out, W_qk, x, ln_g, ln_b, WT, WoT, normed};
    prep_kernel<<<14464, 256, 0, stream>>>(p);
  }
  {  // GEMM1: qk (blocks 0..31, dispatched first) + v->vT | gate (32..1055)
    G8P p{normed, WT, b_hidden, b_qk, os_gamma, os_beta,
          vT, gate, qq, lq, qkh, lkT};
    gemm8p<<<dim3(1056, 1, 1), 512, 73728, stream>>>(p);
  }
  {  // merged: lkv partial slabs (0..511) + attn=relu^2(qq@qkh/256) (512..639)
    GAPP p{vT, lkT, lkvP, qq, qkh, attn};
    gemm_ap<<<dim3(640, 1, 1), 256, 0, stream>>>(p);
  }
  reduce_cvt<<<1024, 256, 0, stream>>>(lkvP, lkvT);
  {  // A3 = gate * (attn @ vg + lin_q @ lin_kv)   (3-slot ring, 2 blocks/CU)
    GQLP p{attn, vT, lq, lkvT, gate, A3};
    gemmQL<<<dim3(512, 1, 1), 512, 73728, stream>>>(p);
  }
  {  // out = A3 @ W_out + b_out + x  (4-slot 8-wave pipelined, 256 blocks)
    GWoP p{A3, WoT, b_out, x, out};
    gemmWo<<<dim3(256, 1, 1), 512, 98304, stream>>>(p);
  }
}

// Round 10
// 288.967 us; speedup vs baseline: 1.0554x; 1.0444x over previous
//
#include <hip/hip_runtime.h>
#include <stdint.h>

typedef __attribute__((ext_vector_type(8))) short bf16x8_t;   // 8 bf16 in 4 VGPRs
typedef __attribute__((ext_vector_type(4))) float f32x4_t;

#define DI __device__ __forceinline__
#define SBAR() asm volatile("s_barrier" ::: "memory")
#define VMW(n) asm volatile("s_waitcnt vmcnt(" #n ")" ::: "memory")

DI unsigned short f2b(float f) {
  union { float f; unsigned int u; } c; c.f = f;
  unsigned int u = c.u + 0x7FFFu + ((c.u >> 16) & 1u);   // RNE
  return (unsigned short)(u >> 16);
}
DI unsigned int pack2(float lo, float hi) {
  return (unsigned int)f2b(lo) | ((unsigned int)f2b(hi) << 16);
}
DI float b2f(unsigned short h) {
  union { unsigned int u; float f; } c; c.u = ((unsigned int)h) << 16;
  return c.f;
}
DI float silu_f(float z) { return z / (1.0f + __expf(-z)); }

// async global->LDS, 16B per lane; LDS dst = wave-uniform base + lane*16B
DI void load_lds16(const unsigned short* g, unsigned short* l) {
  __builtin_amdgcn_global_load_lds(
      (const __attribute__((address_space(1))) unsigned int*)g,
      (__attribute__((address_space(3))) unsigned int*)l,
      16, 0, 0);
}

// ---------------------------------------------------------------- prep mega-kernel
struct PrepP {
  const float *Wh, *Wo, *Wqk, *x, *g, *b;
  unsigned short *WT, *WoT, *normed;
};

__global__ __launch_bounds__(256) void prep_kernel(PrepP p) {
  const int blk = blockIdx.x;
  const int tx = threadIdx.x & 31, ty = threadIdx.x >> 5;
  if (blk < 6272) {
    const float* in; unsigned short* out; int R, C, gx;
    if (blk < 4096)      { in = p.Wh;  out = p.WT;                 R = 1024; C = 4096; gx = blk; }
    else if (blk < 6144) { in = p.Wo;  out = p.WoT;                R = 2048; C = 1024; gx = blk - 4096; }
    else                 { in = p.Wqk; out = p.WT + 4096 * 1024;   R = 1024; C = 128;  gx = blk - 6144; }
    const int xTiles = C >> 5;
    const int c0 = (gx % xTiles) * 32, r0 = (gx / xTiles) * 32;
    __shared__ float tile[32][33];
#pragma unroll
    for (int i = 0; i < 4; ++i)
      tile[ty + 8 * i][tx] = in[(long)(r0 + ty + 8 * i) * C + c0 + tx];
    __syncthreads();
#pragma unroll
    for (int i = 0; i < 4; ++i)
      out[(long)(c0 + ty + 8 * i) * R + r0 + tx] = f2b(tile[tx][ty + 8 * i]);
  } else {
    const int row = blk - 6272, tid = threadIdx.x;
    __shared__ float red[8];
    float4 v = ((const float4*)(p.x + (long)row * 1024))[tid];
    float s = v.x + v.y + v.z + v.w;
    float ss = v.x * v.x + v.y * v.y + v.z * v.z + v.w * v.w;
    for (int o = 32; o > 0; o >>= 1) { s += __shfl_down(s, o); ss += __shfl_down(ss, o); }
    const int wave = tid >> 6, lane = tid & 63;
    if (lane == 0) { red[wave * 2] = s; red[wave * 2 + 1] = ss; }
    __syncthreads();
    if (tid == 0) {
      float S = red[0] + red[2] + red[4] + red[6];
      float SS = red[1] + red[3] + red[5] + red[7];
      float mu = S * (1.0f / 1024.0f);
      float var = SS * (1.0f / 1024.0f) - mu * mu;
      red[0] = mu; red[1] = rsqrtf(var + 1e-5f);
    }
    __syncthreads();
    const float mu = red[0], rstd = red[1];
    float4 gg = ((const float4*)p.g)[tid];
    float4 bb = ((const float4*)p.b)[tid];
    ushort4 o;
    o.x = f2b((v.x - mu) * rstd * gg.x + bb.x);
    o.y = f2b((v.y - mu) * rstd * gg.y + bb.y);
    o.z = f2b((v.z - mu) * rstd * gg.z + bb.z);
    o.w = f2b((v.w - mu) * rstd * gg.w + bb.w);
    ((ushort4*)(p.normed + (long)row * 1024))[tid] = o;
  }
}

// ---------------------------------------------------------------- reduce 8 bf16 slabs -> bf16
__global__ __launch_bounds__(256) void reduce_cvt(
    const unsigned short* __restrict__ part, unsigned short* __restrict__ out) {
  const int idx = blockIdx.x * 256 + threadIdx.x;
  const int b = idx >> 16, i = idx & 65535;
  float4 s = make_float4(0.f, 0.f, 0.f, 0.f);
#pragma unroll
  for (int sl = 0; sl < 8; ++sl) {
    ushort4 v = ((const ushort4*)part)[(long)(b * 8 + sl) * 65536 + i];
    s.x += b2f(v.x); s.y += b2f(v.y); s.z += b2f(v.z); s.w += b2f(v.w);
  }
  ushort4 o;
  o.x = f2b(s.x); o.y = f2b(s.y); o.z = f2b(s.z); o.w = f2b(s.w);
  ((ushort4*)out)[(long)b * 65536 + i] = o;
}

// ---------------------------------------------------------------- 8-wave 256x128 deep-pipelined GEMM1
// R13: XCD A-panel affinity. K-loop aggregate read is ~790MB in 68us = 11.6
// TB/s — L2/L3-served (FETCH only 41.6MB), plausibly L3-BW-bound. Same-bx
// blocks (32 sharers of a 0.5MB A-panel) previously had consecutive ids ->
// spread over all 8 XCDs (A thrashes L2, served from L3). Decomposition swap
// (bx = vg&31 inner, by = vg>>5 outer) puts all 32 sharers in one residue
// class mod 8 (stride 32 == 0 mod 8) -> same XCD; per-XCD A set = 4 panels =
// 2MB <= L2. The LARGER stream (512MB A) moves to the faster cache.
struct G8P {
  const unsigned short* A;
  const unsigned short* B;
  const float* bias;          // b_hidden[4096]
  const float* bias2;         // b_qk[128]
  const float* gamma;         // os_gamma [4][128]
  const float* beta;          // os_beta  [4][128]
  unsigned short* vTout;      // [4][2048 e][2048 n]
  unsigned short* gateOut;    // [8192][2048]
  unsigned short* qqO;        // [8192][128]
  unsigned short* lqO;
  unsigned short* qkhO;
  unsigned short* lkTO;       // [4][128][2048]
};

__global__ __launch_bounds__(512, 4) void gemm8p(G8P p) {
  extern __shared__ unsigned char lds[];   // 3 * 24576 = 73728 B dynamic
  const int tid  = threadIdx.x;
  const int lane = tid & 63;
  const int wave = tid >> 6;
  const bool qk = blockIdx.x < 32;
  int bx, by;
  if (qk) { bx = blockIdx.x; by = 32; }                 // B rows 4096..4223
  else    { const int vg = blockIdx.x - 32; bx = vg & 31; by = vg >> 5; }  // R13 swap
  const int wm = (wave & 1) * 128;
  const int wn = (wave >> 1) * 32;
  const int lm = lane & 15;
  const int kb = lane >> 4;

  // ---- staging coords (pre-swizzled global source; LDS lands linear) ----
  const int rA  = tid >> 2;                                    // 0..127
  const int kby = ((tid & 3) << 4) ^ (((rA >> 1) & 3) << 4);   // 2-way swizzle
  const unsigned short* gA0 = p.A + (long)(bx * 256 + rA) * 1024 + (kby >> 1);
  const unsigned short* gA1 = gA0 + 128 * 1024;
  const int brow = qk ? 4096 : by * 128;
  const unsigned short* gB0 = p.B + (long)(brow + rA) * 1024 + (kby >> 1);

  // ---- fragment-read lane constant ((row>>1)&3 == (lm>>1)&3 for all reps) ----
  const int fxor = (kb << 4) ^ (((lm >> 1) & 3) << 4);

  f32x4_t acc[8][2];
#pragma unroll
  for (int i = 0; i < 8; ++i)
#pragma unroll
    for (int j = 0; j < 2; ++j) acc[i][j] = (f32x4_t){0.f, 0.f, 0.f, 0.f};

  auto stageA = [&](int t) {
    unsigned short* l = (unsigned short*)(lds + (t % 3) * 24576 + wave * 1024);
    load_lds16(gA0 + t * 32, l);
    load_lds16(gA1 + t * 32, (unsigned short*)((unsigned char*)l + 8192));
  };
  auto stageB = [&](int t) {   // 128 rows x 64B = 8KB = 1 load/thread
    unsigned short* l = (unsigned short*)(lds + (t % 3) * 24576 + 16384 + wave * 1024);
    load_lds16(gB0 + t * 32, l);
  };

  // prologue: 2 tiles in flight (6 loads/thread)
#pragma unroll
  for (int u = 0; u < 2; ++u) { stageA(u); stageB(u); }
  VMW(3);
  SBAR();

  constexpr int NT = 16;   // K=1024 / BK=32
#pragma unroll 1
  for (int t = 0; t < NT; ++t) {
    const unsigned char* slot = lds + (t % 3) * 24576;
    bf16x8_t bF[2], aF[4];
#pragma unroll
    for (int j = 0; j < 2; ++j)
      bF[j] = *(const bf16x8_t*)(slot + 16384 + (wn + j * 16 + lm) * 64 + fxor);
#pragma unroll
    for (int i = 0; i < 4; ++i)
      aF[i] = *(const bf16x8_t*)(slot + (wm + i * 16 + lm) * 64 + fxor);
    if (t <= NT - 3) stageA(t + 2);
    __builtin_amdgcn_s_setprio(1);
#pragma unroll
    for (int i = 0; i < 4; ++i)
#pragma unroll
      for (int j = 0; j < 2; ++j)
        acc[i][j] = __builtin_amdgcn_mfma_f32_16x16x32_bf16(aF[i], bF[j], acc[i][j], 0, 0, 0);
    __builtin_amdgcn_s_setprio(0);
#pragma unroll
    for (int i = 0; i < 4; ++i)
      aF[i] = *(const bf16x8_t*)(slot + (wm + 64 + i * 16 + lm) * 64 + fxor);
    if (t <= NT - 3) stageB(t + 2);
    __builtin_amdgcn_s_setprio(1);
#pragma unroll
    for (int i = 0; i < 4; ++i)
#pragma unroll
      for (int j = 0; j < 2; ++j)
        acc[i + 4][j] = __builtin_amdgcn_mfma_f32_16x16x32_bf16(aF[i], bF[j], acc[i + 4][j], 0, 0, 0);
    __builtin_amdgcn_s_setprio(0);
    if (t <= NT - 3)      { VMW(3); }
    else if (t == NT - 2) { VMW(0); }
    SBAR();   // single barrier per tile
  }

  // ---------------- epilogue ----------------
  if (qk) {
    // silu -> LDS [256][136] -> OffsetScale+RoPE. All 8 waves write (BN=128).
    unsigned short* q16 = (unsigned short*)lds;   // 69632 B <= 73728
#pragma unroll
    for (int i = 0; i < 8; ++i) {
      const int rloc = wm + i * 16 + (lane >> 4) * 4;   // 0..255
#pragma unroll
      for (int j = 0; j < 2; ++j) {
        const int cl = wn + j * 16 + lm;                // 0..127
        const float bb = p.bias2[cl];
#pragma unroll
        for (int r = 0; r < 4; ++r)
          q16[(rloc + r) * 136 + cl] = f2b(silu_f(acc[i][j][r] + bb));
      }
    }
    __syncthreads();
    const int j = tid & 63;
    const int rq = tid >> 6;                              // 0..7
    const float freq = powf(10000.0f, (float)j * (1.0f / 64.0f));
    float ga[4], gb[4], ea[4], eb[4];
#pragma unroll
    for (int h = 0; h < 4; ++h) {
      ga[h] = p.gamma[h * 128 + j];  gb[h] = p.gamma[h * 128 + 64 + j];
      ea[h] = p.beta[h * 128 + j];   eb[h] = p.beta[h * 128 + 64 + j];
    }
    unsigned short* outs[3] = {p.qqO, p.lqO, p.qkhO};
    for (int rr = 0; rr < 32; ++rr) {
      const int row = rr * 8 + rq;                        // 0..255
      const float x1 = b2f(q16[row * 136 + j]);
      const float x2 = b2f(q16[row * 136 + 64 + j]);
      const int tok = bx * 256 + row;
      const int pos = tok & 2047, bidx = tok >> 11;
      const float ang = (float)pos * freq;
      const float sn = sinf(ang), cs = cosf(ang);
#pragma unroll
      for (int h = 0; h < 3; ++h) {
        const float y1 = x1 * ga[h] + ea[h], y2 = x2 * gb[h] + eb[h];
        outs[h][(long)tok * 128 + j] = f2b(y1 * cs - y2 * sn);
        outs[h][(long)tok * 128 + 64 + j] = f2b(y2 * cs + y1 * sn);
      }
      const float y1 = x1 * ga[3] + ea[3], y2 = x2 * gb[3] + eb[3];
      p.lkTO[((long)bidx * 128 + j) * 2048 + pos] = f2b(y1 * cs - y2 * sn);
      p.lkTO[((long)bidx * 128 + 64 + j) * 2048 + pos] = f2b(y2 * cs + y1 * sn);
    }
  } else if (by < 16) {
    // v half: silu+bias, pack pairs, 256x128 transpose via [128][128]-uint LDS
    // (64KB), chunk-XOR (e&7) kills conflicts; coalesced 512B vT row stores.
    unsigned int* Cx = (unsigned int*)lds;
#pragma unroll
    for (int i = 0; i < 8; ++i) {
      const int c0 = (wm + i * 16) / 2 + (lane >> 4) * 2;   // even uint col 0..127
#pragma unroll
      for (int j = 0; j < 2; ++j) {
        const int e = wn + j * 16 + lm;                     // 0..127
        const float bb = p.bias[by * 128 + e];
        const float s0 = silu_f(acc[i][j][0] + bb);
        const float s1 = silu_f(acc[i][j][1] + bb);
        const float s2 = silu_f(acc[i][j][2] + bb);
        const float s3 = silu_f(acc[i][j][3] + bb);
        const int x = (e & 7) << 2;
        Cx[e * 128 + (c0 ^ x)]     = pack2(s0, s1);
        Cx[e * 128 + (c0 ^ x) + 1] = pack2(s2, s3);
      }
    }
    __syncthreads();
    const int bq = bx >> 3, nloc0 = (bx & 7) * 256, e0g = by * 128;
    unsigned short* dstBase = p.vTout + ((long)(bq * 2048 + e0g)) * 2048 + nloc0;
#pragma unroll
    for (int rep = 0; rep < 8; ++rep) {
      const int flat = rep * 512 + tid;
      const int e = flat >> 5, q = flat & 31;
      uint4 val = *(const uint4*)(Cx + e * 128 + ((q ^ (e & 7)) << 2));
      *(uint4*)(dstBase + (long)e * 2048 + q * 8) = val;
    }
  } else {
    // gate half: cols 2048 + (by-16)*128 ..
#pragma unroll
    for (int i = 0; i < 8; ++i) {
      const int row0 = bx * 256 + wm + i * 16 + (lane >> 4) * 4;
#pragma unroll
      for (int j = 0; j < 2; ++j) {
        const int colg = (by - 16) * 128 + wn + j * 16 + lm;   // 0..2047
        const float bb = p.bias[2048 + colg];
#pragma unroll
        for (int r = 0; r < 4; ++r)
          p.gateOut[(long)(row0 + r) * 2048 + colg] =
              f2b(silu_f(acc[i][j][r] + bb));
      }
    }
  }
}

// ---------------------------------------------------------------- QUADLIN: A3 = gate*(attn@vg + lq@lkv)
struct GQLP {
  const unsigned short* attn;   // [32][256][256]
  const unsigned short* vT;     // [4][2048][2048]
  const unsigned short* lq;     // [8192][128]
  const unsigned short* lkvT;   // [4][2048][128]
  const unsigned short* gateIn; // [8192][2048]
  unsigned short* outU;         // A3 [8192][2048]
};

__global__ __launch_bounds__(512, 4) void gemmQL(GQLP p) {
  extern __shared__ unsigned char lds[];   // 3 * 24576 = 73728 B dynamic
  const int tid  = threadIdx.x;
  const int lane = tid & 63;
  const int wave = tid >> 6;
  const int z  = blockIdx.x >> 4;    // 0..31 (b*8+g)
  const int by = blockIdx.x & 15;    // 0..15 (n-tile of 2048, 128 wide)
  const int b = z >> 3, g = z & 7;
  const int wm = (wave & 1) * 128;
  const int wn = (wave >> 1) * 32;
  const int lm = lane & 15;
  const int kb = lane >> 4;

  const int rA  = tid >> 2;                                    // 0..127
  const int kby = ((tid & 3) << 4) ^ (((rA >> 1) & 3) << 4);
  const int swz = kby >> 1;                                    // shorts
  const unsigned short* a1 = p.attn + (long)z * 65536 + rA * 256 + swz;
  const unsigned short* a2 = p.lq + ((long)z * 256 + rA) * 128 + swz;
  const unsigned short* b1 = p.vT + (long)b * 4194304 + (long)(by * 128 + rA) * 2048 + g * 256 + swz;
  const unsigned short* b2 = p.lkvT + (long)b * 262144 + (by * 128 + rA) * 128 + swz;
  const int fxor = (kb << 4) ^ (((lm >> 1) & 3) << 4);

  f32x4_t acc[8][2];
#pragma unroll
  for (int i = 0; i < 8; ++i)
#pragma unroll
    for (int j = 0; j < 2; ++j) acc[i][j] = (f32x4_t){0.f, 0.f, 0.f, 0.f};

  auto stageA = [&](int tt) {
    unsigned char* base = lds + (tt % 3) * 24576;
    unsigned short* l  = (unsigned short*)(base + wave * 1024);
    unsigned short* lh = (unsigned short*)(base + wave * 1024 + 8192);
    if (tt < 8) { load_lds16(a1 + tt * 32, l); load_lds16(a1 + 128 * 256 + tt * 32, lh); }
    else { const int k2 = (tt - 8) * 32;
           load_lds16(a2 + k2, l); load_lds16(a2 + 128 * 128 + k2, lh); }
  };
  auto stageB = [&](int tt) {   // 128 rows x 64B = 8KB = 1 load/thread
    unsigned short* l = (unsigned short*)(lds + (tt % 3) * 24576 + 16384 + wave * 1024);
    if (tt < 8) load_lds16(b1 + tt * 32, l);
    else        load_lds16(b2 + (tt - 8) * 32, l);
  };

#pragma unroll
  for (int u = 0; u < 2; ++u) { stageA(u); stageB(u); }   // 6 in flight
  VMW(3);
  SBAR();

  constexpr int NT = 12;   // 8 (K=256 phase1) + 4 (K=128 phase2)
#pragma unroll 1
  for (int t = 0; t < NT; ++t) {
    const unsigned char* slot = lds + (t % 3) * 24576;
    bf16x8_t bF[2], aF[4];
#pragma unroll
    for (int j = 0; j < 2; ++j)
      bF[j] = *(const bf16x8_t*)(slot + 16384 + (wn + j * 16 + lm) * 64 + fxor);
#pragma unroll
    for (int i = 0; i < 4; ++i)
      aF[i] = *(const bf16x8_t*)(slot + (wm + i * 16 + lm) * 64 + fxor);
    if (t <= NT - 3) stageA(t + 2);
    __builtin_amdgcn_s_setprio(1);
#pragma unroll
    for (int i = 0; i < 4; ++i)
#pragma unroll
      for (int j = 0; j < 2; ++j)
        acc[i][j] = __builtin_amdgcn_mfma_f32_16x16x32_bf16(aF[i], bF[j], acc[i][j], 0, 0, 0);
    __builtin_amdgcn_s_setprio(0);
#pragma unroll
    for (int i = 0; i < 4; ++i)
      aF[i] = *(const bf16x8_t*)(slot + (wm + 64 + i * 16 + lm) * 64 + fxor);
    if (t <= NT - 3) stageB(t + 2);
    __builtin_amdgcn_s_setprio(1);
#pragma unroll
    for (int i = 0; i < 4; ++i)
#pragma unroll
      for (int j = 0; j < 2; ++j)
        acc[i + 4][j] = __builtin_amdgcn_mfma_f32_16x16x32_bf16(aF[i], bF[j], acc[i + 4][j], 0, 0, 0);
    __builtin_amdgcn_s_setprio(0);
    if (t <= NT - 3)      { VMW(3); }
    else if (t == NT - 2) { VMW(0); }
    SBAR();
  }

  // epilogue: A3 = gate * acc
#pragma unroll
  for (int i = 0; i < 8; ++i) {
    const int row0 = z * 256 + wm + i * 16 + (lane >> 4) * 4;
#pragma unroll
    for (int j = 0; j < 2; ++j) {
      const int col = by * 128 + wn + j * 16 + lm;
#pragma unroll
      for (int r = 0; r < 4; ++r) {
        const long idx = (long)(row0 + r) * 2048 + col;
        p.outU[idx] = f2b(b2f(p.gateIn[idx]) * acc[i][j][r]);
      }
    }
  }
}

// ---------------------------------------------------------------- FINAL: A3 @ WoT + b_out + x
// R13: same XCD A-panel affinity swap (bx inner): same-bx blocks (8 sharers of
// a 1MB A3 panel) now land on one XCD -> panel L2-resident (4 panels = 4MB).
struct GWoP {
  const unsigned short* A;   // A3 [8192][2048]
  const unsigned short* B;   // WoT [1024][2048]
  const float* bias;         // b_out[1024]
  const float* xres;         // x fp32 [8192][1024]
  float* outF;               // [8192][1024]
};

__global__ __launch_bounds__(512, 2) void gemmWo(GWoP p) {
  extern __shared__ unsigned char lds[];   // 4 * 24576 = 98304 B dynamic
  const int tid  = threadIdx.x;
  const int lane = tid & 63;
  const int wave = tid >> 6;
  const int bx = blockIdx.x & 31;          // R13: m-tile inner (same-bx -> same XCD)
  const int by = blockIdx.x >> 5;          // 0..7 (n-tile, 128 cols)
  const int wm = (wave & 1) * 128;
  const int wn = (wave >> 1) * 32;         // 4 n-groups of 32
  const int lm = lane & 15;
  const int kb = lane >> 4;

  const int rA  = tid >> 2;                                    // 0..127
  const int kby = ((tid & 3) << 4) ^ (((rA >> 1) & 3) << 4);
  const unsigned short* gA0 = p.A + (long)(bx * 256 + rA) * 2048 + (kby >> 1);
  const unsigned short* gA1 = gA0 + 128 * 2048;
  const unsigned short* gB0 = p.B + (long)(by * 128 + rA) * 2048 + (kby >> 1);
  const int fxor = (kb << 4) ^ (((lm >> 1) & 3) << 4);

  f32x4_t acc[8][2];
#pragma unroll
  for (int i = 0; i < 8; ++i)
#pragma unroll
    for (int j = 0; j < 2; ++j) acc[i][j] = (f32x4_t){0.f, 0.f, 0.f, 0.f};

  auto stageA = [&](int t) {
    unsigned short* l = (unsigned short*)(lds + (t & 3) * 24576 + wave * 1024);
    load_lds16(gA0 + t * 32, l);
    load_lds16(gA1 + t * 32, (unsigned short*)((unsigned char*)l + 8192));
  };
  auto stageB = [&](int t) {   // 128 rows x 64B = 8KB = 1 load/thread
    unsigned short* l = (unsigned short*)(lds + (t & 3) * 24576 + 16384 + wave * 1024);
    load_lds16(gB0 + t * 32, l);
  };

#pragma unroll
  for (int u = 0; u < 3; ++u) { stageA(u); stageB(u); }   // 9 in flight
  VMW(6);
  SBAR();

  constexpr int NT = 64;   // K=2048 / BK=32
#pragma unroll 1
  for (int t = 0; t < NT; ++t) {
    const unsigned char* slot = lds + (t & 3) * 24576;
    bf16x8_t bF[2], aF[4];
#pragma unroll
    for (int j = 0; j < 2; ++j)
      bF[j] = *(const bf16x8_t*)(slot + 16384 + (wn + j * 16 + lm) * 64 + fxor);
#pragma unroll
    for (int i = 0; i < 4; ++i)
      aF[i] = *(const bf16x8_t*)(slot + (wm + i * 16 + lm) * 64 + fxor);
    if (t <= NT - 4) stageA(t + 3);
    __builtin_amdgcn_s_setprio(1);
#pragma unroll
    for (int i = 0; i < 4; ++i)
#pragma unroll
      for (int j = 0; j < 2; ++j)
        acc[i][j] = __builtin_amdgcn_mfma_f32_16x16x32_bf16(aF[i], bF[j], acc[i][j], 0, 0, 0);
    __builtin_amdgcn_s_setprio(0);
#pragma unroll
    for (int i = 0; i < 4; ++i)
      aF[i] = *(const bf16x8_t*)(slot + (wm + 64 + i * 16 + lm) * 64 + fxor);
    if (t <= NT - 4) stageB(t + 3);
    __builtin_amdgcn_s_setprio(1);
#pragma unroll
    for (int i = 0; i < 4; ++i)
#pragma unroll
      for (int j = 0; j < 2; ++j)
        acc[i + 4][j] = __builtin_amdgcn_mfma_f32_16x16x32_bf16(aF[i], bF[j], acc[i + 4][j], 0, 0, 0);
    __builtin_amdgcn_s_setprio(0);
    if (t <= NT - 4)      { VMW(6); }
    else if (t == NT - 3) { VMW(3); }
    else if (t == NT - 2) { VMW(0); }
    SBAR();
  }

  // epilogue: + bias + x residual, fp32 out
#pragma unroll
  for (int i = 0; i < 8; ++i) {
    const int row0 = bx * 256 + wm + i * 16 + (lane >> 4) * 4;
#pragma unroll
    for (int j = 0; j < 2; ++j) {
      const int col = by * 128 + wn + j * 16 + lm;
      const float bb = p.bias[col];
#pragma unroll
      for (int r = 0; r < 4; ++r) {
        const long idx = (long)(row0 + r) * 1024 + col;
        p.outF[idx] = acc[i][j][r] + bb + p.xres[idx];
      }
    }
  }
}

// ---------------------------------------------------------------- merged ARELU + LKV-PART dispatch
struct GAPP {
  const unsigned short* vT;    // [4][2048][2048]
  const unsigned short* lkT;   // [4][128][2048]
  unsigned short* lkvP;        // [32 slabs][2048][128]
  const unsigned short* qq;    // [8192][128]
  const unsigned short* qkh;   // [8192][128]
  unsigned short* attn;        // [32][256][256]
};

__global__ __launch_bounds__(256, 2) void gemm_ap(GAPP p) {
  __shared__ __align__(16) unsigned char smem[16384];
  unsigned short* As = (unsigned short*)smem;             // [128][32] bf16
  unsigned short* Bs = (unsigned short*)(smem + 8192);    // [128][32] bf16

  const int tid = threadIdx.x;
  const int lane = tid & 63;
  const int wave = tid >> 6;
  const bool isPart = blockIdx.x < 512;

  unsigned short* lA = As + wave * 32 * 32;
  unsigned short* lB = Bs + wave * 32 * 32;
  const int wm = (wave & 1) * 64;
  const int wn = (wave >> 1) * 64;
  const int lm = lane & 15;
  const int kb = lane >> 4;
  const int rowSel = (wave * 32 + (lane >> 2));   // staging row within 128-tile
  const int colSel = (lane & 3) * 8;              // staging k-offset

  const unsigned short* Ag;
  const unsigned short* Bg;
  int lda, ldb, ksteps;
  int zi, bxi, byi;
  if (isPart) {
    zi  = blockIdx.x >> 4;             // 0..31 (b*8+s)
    bxi = blockIdx.x & 15;             // m-tile of 2048
    byi = 0;
    const int b = zi >> 3, s = zi & 7;
    Ag = p.vT + (long)b * 4194304 + (long)(bxi * 128 + rowSel) * 2048 + s * 256 + colSel;
    Bg = p.lkT + (long)b * 262144 + (long)rowSel * 2048 + s * 256 + colSel;
    lda = 2048; ldb = 2048; ksteps = 8;   // K=256
  } else {
    const int a = blockIdx.x - 512;    // 0..127
    zi  = a >> 2;                      // 0..31
    bxi = (a >> 1) & 1;
    byi = a & 1;
    Ag = p.qq  + ((long)zi * 256 + bxi * 128 + rowSel) * 128 + colSel;
    Bg = p.qkh + ((long)zi * 256 + byi * 128 + rowSel) * 128 + colSel;
    lda = 128; ldb = 128; ksteps = 4;     // K=128
  }

  f32x4_t acc[4][4];
#pragma unroll
  for (int i = 0; i < 4; ++i)
#pragma unroll
    for (int j = 0; j < 4; ++j) acc[i][j] = (f32x4_t){0.f, 0.f, 0.f, 0.f};

  const int a16 = 16 * lda, b16 = 16 * ldb;
  for (int kt = 0; kt < ksteps; ++kt) {
    load_lds16(Ag, lA);
    load_lds16(Ag + a16, lA + 512);
    load_lds16(Bg, lB);
    load_lds16(Bg + b16, lB + 512);
    Ag += 32; Bg += 32;
    __syncthreads();
    bf16x8_t aF[4], bF[4];
#pragma unroll
    for (int i = 0; i < 4; ++i)
      aF[i] = *(const bf16x8_t*)(As + (wm + i * 16 + lm) * 32 + kb * 8);
#pragma unroll
    for (int j = 0; j < 4; ++j)
      bF[j] = *(const bf16x8_t*)(Bs + (wn + j * 16 + lm) * 32 + kb * 8);
#pragma unroll
    for (int i = 0; i < 4; ++i)
#pragma unroll
      for (int j = 0; j < 4; ++j)
        acc[i][j] = __builtin_amdgcn_mfma_f32_16x16x32_bf16(aF[i], bF[j], acc[i][j], 0, 0, 0);
    __syncthreads();
  }

  if (isPart) {
    unsigned short* slab = p.lkvP + (long)zi * 262144;
#pragma unroll
    for (int i = 0; i < 4; ++i) {
      const int row0 = bxi * 128 + wm + i * 16 + (lane >> 4) * 4;
#pragma unroll
      for (int j = 0; j < 4; ++j) {
        const int col = wn + j * 16 + lm;   // 0..127
#pragma unroll
        for (int r = 0; r < 4; ++r)
          slab[(row0 + r) * 128 + col] = f2b(acc[i][j][r] * (1.0f / 2048.0f));
      }
    }
  } else {
    unsigned short* outA = p.attn + (long)zi * 65536;
#pragma unroll
    for (int i = 0; i < 4; ++i) {
      const int row0 = bxi * 128 + wm + i * 16 + (lane >> 4) * 4;
#pragma unroll
      for (int j = 0; j < 4; ++j) {
        const int col = byi * 128 + wn + j * 16 + lm;
#pragma unroll
        for (int r = 0; r < 4; ++r) {
          float s = acc[i][j][r] * (1.0f / 256.0f);
          s = s > 0.f ? s : 0.f;
          outA[(row0 + r) * 256 + col] = f2b(s * s);
        }
      }
    }
  }
}

// ---------------------------------------------------------------- launch
extern "C" void kernel_launch(void* const* d_in, const int* in_sizes, int n_in,
                              void* d_out, int out_size, void* d_ws, size_t ws_size,
                              hipStream_t stream) {
  const float* x        = (const float*)d_in[0];
  const float* ln_g     = (const float*)d_in[1];
  const float* ln_b     = (const float*)d_in[2];
  const float* W_hidden = (const float*)d_in[3];
  const float* b_hidden = (const float*)d_in[4];
  const float* W_qk     = (const float*)d_in[5];
  const float* b_qk     = (const float*)d_in[6];
  const float* os_gamma = (const float*)d_in[7];
  const float* os_beta  = (const float*)d_in[8];
  const float* W_out    = (const float*)d_in[9];
  const float* b_out    = (const float*)d_in[10];
  float* out = (float*)d_out;

  char* w = (char*)d_ws;
  auto ws = [&](size_t bytes) { char* p = w; w += bytes; return (unsigned short*)p; };
  unsigned short* WT     = ws(8650752);   // [4224][1024] bf16 (Wh cols | Wqk cols)
  unsigned short* WoT    = ws(4194304);   // [1024][2048]
  unsigned short* normed = ws(16777216);  // [8192][1024]
  unsigned short* vT     = ws(33554432);  // [4][2048 e][2048 n]
  unsigned short* gate   = ws(33554432);  // [8192][2048]
  unsigned short* qq     = ws(2097152);
  unsigned short* qkh    = ws(2097152);
  unsigned short* lq     = ws(2097152);
  unsigned short* lkT    = ws(2097152);   // [4][128][2048]
  unsigned short* attn   = ws(4194304);   // [32][256][256]
  unsigned short* lkvP   = ws(16777216);  // [32 slabs][2048][128] bf16 partials
  unsigned short* lkvT   = ws(2097152);   // [4][2048 e][128 d] bf16
  unsigned short* A3     = ws(33554432);  // [8192][2048]

  static bool s_attr = false;
  if (!s_attr) {
    hipFuncSetAttribute((const void*)gemm8p,
                        hipFuncAttributeMaxDynamicSharedMemorySize, 73728);
    hipFuncSetAttribute((const void*)gemmQL,
                        hipFuncAttributeMaxDynamicSharedMemorySize, 73728);
    hipFuncSetAttribute((const void*)gemmWo,
                        hipFuncAttributeMaxDynamicSharedMemorySize, 98304);
    s_attr = true;
  }

  {  // weight transposes + layernorm in one dispatch
    PrepP p{W_hidden, W_out, W_qk, x, ln_g, ln_b, WT, WoT, normed};
    prep_kernel<<<14464, 256, 0, stream>>>(p);
  }
  {  // GEMM1: qk (blocks 0..31, dispatched first) + v->vT | gate (32..1055)
    G8P p{normed, WT, b_hidden, b_qk, os_gamma, os_beta,
          vT, gate, qq, lq, qkh, lkT};
    gemm8p<<<dim3(1056, 1, 1), 512, 73728, stream>>>(p);
  }
  {  // merged: lkv partial slabs (0..511) + attn=relu^2(qq@qkh/256) (512..639)
    GAPP p{vT, lkT, lkvP, qq, qkh, attn};
    gemm_ap<<<dim3(640, 1, 1), 256, 0, stream>>>(p);
  }
  reduce_cvt<<<1024, 256, 0, stream>>>(lkvP, lkvT);
  {  // A3 = gate * (attn @ vg + lin_q @ lin_kv)   (3-slot ring, 2 blocks/CU)
    GQLP p{attn, vT, lq, lkvT, gate, A3};
    gemmQL<<<dim3(512, 1, 1), 512, 73728, stream>>>(p);
  }
  {  // out = A3 @ W_out + b_out + x  (4-slot 8-wave pipelined, 256 blocks)
    GWoP p{A3, WoT, b_out, x, out};
    gemmWo<<<dim3(256, 1, 1), 512, 98304, stream>>>(p);
  }
}